// Round 9
// baseline (168.588 us; speedup 1.0000x reference)
//
#include <hip/hip_runtime.h>
#include <hip/hip_bf16.h>

#define CC 256
#define DD 64
#define PP 18
#define ROWS 32768
#define EPSF 1e-5f

typedef __attribute__((ext_vector_type(8))) short bf16x8;
typedef __attribute__((ext_vector_type(4))) short s16x4;
typedef __attribute__((ext_vector_type(4))) float f32x4;

// ---------------------------------------------------------------------------
// Pack qkv + Wo weights into 16x16 MFMA B-fragment order (bf16).
__global__ __launch_bounds__(256) void k_pack_all(
    const float* __restrict__ Wq, const float* __restrict__ Wk,
    const float* __restrict__ Wv, const float* __restrict__ Wo,
    __hip_bfloat16* __restrict__ WqP, __hip_bfloat16* __restrict__ WkP,
    __hip_bfloat16* __restrict__ WvP, __hip_bfloat16* __restrict__ WoP) {
    int i = blockIdx.x * 256 + threadIdx.x;
    const float* src; __hip_bfloat16* dst; int K, N, j;
    if (i < 16384)       { src = Wq; dst = WqP; K = 256;  N = 64;   j = i; }
    else if (i < 32768)  { src = Wk; dst = WkP; K = 256;  N = 64;   j = i - 16384; }
    else if (i < 49152)  { src = Wv; dst = WvP; K = 256;  N = 64;   j = i - 32768; }
    else                 { src = Wo; dst = WoP; K = 64;   N = 256;  j = i - 49152; }
    int e = j & 7, l = (j >> 3) & 63, rest = j >> 9;
    int KS = K >> 5;
    int ks = rest % KS, nt = rest / KS;
    int row = ks * 32 + (l >> 4) * 8 + e;
    int col = nt * 16 + (l & 15);
    dst[j] = __float2bfloat16(src[(long)row * N + col]);
}

// ---------------------------------------------------------------------------
// Transpose W1 -> W1T [1024][256] (n-major) and W2 -> W2T [2][256][512]
// (two K-halves, each n-major k-contiguous), fp32 -> bf16.
__global__ __launch_bounds__(256) void k_wt(const float* __restrict__ W1,
                                            const float* __restrict__ W2,
                                            __hip_bfloat16* __restrict__ W1T,
                                            __hip_bfloat16* __restrict__ W2T) {
    int i = blockIdx.x * 256 + threadIdx.x;
    if (i < 262144) {
        int n = i >> 8, k = i & 255;
        W1T[i] = __float2bfloat16(W1[k * 1024 + n]);
    } else {
        int j = i - 262144;
        int h = j >> 17, n = (j >> 9) & 255, kk = j & 511;
        W2T[j] = __float2bfloat16(W2[(long)(h * 512 + kk) * 256 + n]);
    }
}

// ---------------------------------------------------------------------------
// Fused QKV. 32 rows/block, 4 waves, 16x16 MFMA, A-frags hoisted.
__global__ __launch_bounds__(256) void k_qkv(
    const float4* __restrict__ X4, const float4* __restrict__ pe4,
    const __hip_bfloat16* __restrict__ WqP, const __hip_bfloat16* __restrict__ WkP,
    const __hip_bfloat16* __restrict__ WvP,
    const float* __restrict__ bq, const float* __restrict__ bk,
    const float* __restrict__ bv,
    __hip_bfloat16* __restrict__ Xpb,
    __hip_bfloat16* __restrict__ Qb, __hip_bfloat16* __restrict__ Kb,
    __hip_bfloat16* __restrict__ Vb) {
    __shared__ short Xs[32 * 256];      // 16 KB, swizzled
    const int t = threadIdx.x, w = t >> 6, l = t & 63;
    const int l15 = l & 15, lh = l >> 4;
    const int row0 = blockIdx.x * 32;

    for (int j = t; j < 2048; j += 256) {          // 32 rows x 64 float4
        int r = j >> 6, c4 = j & 63;
        long g = row0 + r;
        float4 a = X4[(g << 6) + c4];
        float4 p = pe4[(long)((g & 16383) << 6) + c4];
        union { s16x4 v; __hip_bfloat16 h[4]; } u;
        u.h[0] = __float2bfloat16(a.x + p.x);
        u.h[1] = __float2bfloat16(a.y + p.y);
        u.h[2] = __float2bfloat16(a.z + p.z);
        u.h[3] = __float2bfloat16(a.w + p.w);
        int db = (r << 9) + (c4 << 3);
        db ^= (r & 7) << 4;
        *(s16x4*)((char*)Xs + db) = u.v;
        *(s16x4*)((char*)Xpb + (g << 9) + (c4 << 3)) = u.v;
    }
    __syncthreads();

    bf16x8 af[2][8];
#pragma unroll
    for (int ri = 0; ri < 2; ++ri)
#pragma unroll
        for (int ks = 0; ks < 8; ++ks) {
            int r = ri * 16 + l15;
            int db = (r << 9) + ks * 64 + lh * 16;
            db ^= (r & 7) << 4;
            af[ri][ks] = *(const bf16x8*)((const char*)Xs + db);
        }

    f32x4 acc[3][2];
#pragma unroll
    for (int j = 0; j < 3; ++j)
#pragma unroll
        for (int ri = 0; ri < 2; ++ri) acc[j][ri] = (f32x4)(0.f);

#pragma unroll
    for (int ks = 0; ks < 8; ++ks)
#pragma unroll
        for (int j = 0; j < 3; ++j) {
            int nt = w * 3 + j;
            const __hip_bfloat16* WP = (nt < 4) ? WqP : ((nt < 8) ? WkP : WvP);
            int ntl = nt & 3;
            bf16x8 b = *(const bf16x8*)(WP + (long)(((ntl * 8 + ks) << 6) + l) * 8);
#pragma unroll
            for (int ri = 0; ri < 2; ++ri)
                acc[j][ri] = __builtin_amdgcn_mfma_f32_16x16x32_bf16(
                    af[ri][ks], b, acc[j][ri], 0, 0, 0);
        }

#pragma unroll
    for (int j = 0; j < 3; ++j) {
        int nt = w * 3 + j;
        __hip_bfloat16* OP = (nt < 4) ? Qb : ((nt < 8) ? Kb : Vb);
        const float* BP = (nt < 4) ? bq : ((nt < 8) ? bk : bv);
        int col = (nt & 3) * 16 + l15;
        float bias = BP[col];
#pragma unroll
        for (int ri = 0; ri < 2; ++ri)
#pragma unroll
            for (int rg = 0; rg < 4; ++rg) {
                long row = row0 + ri * 16 + lh * 4 + rg;
                OP[row * DD + col] = __float2bfloat16(acc[j][ri][rg] + bias);
            }
    }
}

// ---------------------------------------------------------------------------
// Gather-attention, bf16 K/V. One wave per token.
__global__ __launch_bounds__(256) void k_attn(const __hip_bfloat16* __restrict__ Q,
                                              const __hip_bfloat16* __restrict__ K,
                                              const __hip_bfloat16* __restrict__ V,
                                              const int* __restrict__ sel,
                                              __hip_bfloat16* __restrict__ ctx,
                                              float* __restrict__ attn_out) {
    const int wave  = threadIdx.x >> 6;
    const int lane  = threadIdx.x & 63;
    const int token = blockIdx.x * 4 + wave;
    const int b     = token >> 14;
    const float q   = __bfloat162float(Q[token * DD + lane]);

    int   idx[PP];
    float sc[PP];
    const int* selp = sel + (long)token * PP;
#pragma unroll
    for (int p = 0; p < PP; ++p) idx[p] = selp[p];

#pragma unroll
    for (int p = 0; p < PP; ++p) {
        float v = q * __bfloat162float(K[(((b << 14) + idx[p]) << 6) + lane]);
#pragma unroll
        for (int o = 32; o > 0; o >>= 1) v += __shfl_xor(v, o);
        sc[p] = v * 0.125f;
    }

    float mx = sc[0];
#pragma unroll
    for (int p = 1; p < PP; ++p) mx = fmaxf(mx, sc[p]);
    float e[PP];
    float s = 0.f;
#pragma unroll
    for (int p = 0; p < PP; ++p) { e[p] = expf(sc[p] - mx); s += e[p]; }
    const float inv = 1.f / s;

    float aval = 0.f;
#pragma unroll
    for (int p = 0; p < PP; ++p) aval = (lane == p) ? e[p] * inv : aval;
    if (lane < PP) attn_out[(long)token * PP + lane] = aval;

    float cv = 0.f;
#pragma unroll
    for (int p = 0; p < PP; ++p)
        cv += (e[p] * inv) * __bfloat162float(V[(((b << 14) + idx[p]) << 6) + lane]);
    ctx[token * DD + lane] = __float2bfloat16(cv);
}

// ---------------------------------------------------------------------------
// proj + LN1: Xn = LN(Xpb + ctx@Wo + bo)*g1 + be1 -> bf16 (called IN-PLACE:
// Xnb == Xpb; all reads of a row happen before the post-barrier writes).
__global__ __launch_bounds__(256) void k_projln(
    const __hip_bfloat16* __restrict__ ctx, const __hip_bfloat16* __restrict__ WoP,
    const float* __restrict__ bo, const float* __restrict__ g1,
    const float* __restrict__ be1,
    const __hip_bfloat16* __restrict__ Xpb, __hip_bfloat16* __restrict__ Xnb) {
    __shared__ short Cs[32 * 64];       // 4 KB, swizzled
    __shared__ float red[2][32][2];
    __shared__ float mrs[32][2];
    const int t = threadIdx.x, w = t >> 6, l = t & 63;
    const int l15 = l & 15, lh = l >> 4;
    const int row0 = blockIdx.x * 32;

    {
        int r = t >> 3, ch = t & 7;                // 32 rows x 8 x 16B = 256
        int db = (r << 7) + (ch << 4);
        db ^= (r & 7) << 4;
        *(bf16x8*)((char*)Cs + db) = *(const bf16x8*)(ctx + (long)(row0 + r) * DD + ch * 8);
    }
    __syncthreads();

    const int ri = w & 1, nh = w >> 1;

    bf16x8 af[2];
#pragma unroll
    for (int ks = 0; ks < 2; ++ks) {
        int r = ri * 16 + l15;
        int db = (r << 7) + ks * 64 + lh * 16;
        db ^= (r & 7) << 4;
        af[ks] = *(const bf16x8*)((const char*)Cs + db);
    }

    f32x4 acc[8];
#pragma unroll
    for (int j = 0; j < 8; ++j) acc[j] = (f32x4)(0.f);

#pragma unroll
    for (int ks = 0; ks < 2; ++ks)
#pragma unroll
        for (int j = 0; j < 8; ++j) {
            int nt = nh * 8 + j;
            bf16x8 b = *(const bf16x8*)(WoP + (long)(((nt * 2 + ks) << 6) + l) * 8);
            acc[j] = __builtin_amdgcn_mfma_f32_16x16x32_bf16(af[ks], b, acc[j], 0, 0, 0);
        }

    float bov[8], g1v[8], be1v[8];
#pragma unroll
    for (int j = 0; j < 8; ++j) {
        int col = (nh * 8 + j) * 16 + l15;
        bov[j] = bo[col]; g1v[j] = g1[col]; be1v[j] = be1[col];
    }

    float xv[4][8];
#pragma unroll
    for (int rg = 0; rg < 4; ++rg) {
        long grow = row0 + ri * 16 + lh * 4 + rg;
        float s = 0.f, q = 0.f;
#pragma unroll
        for (int j = 0; j < 8; ++j) {
            float v = acc[j][rg] + bov[j] +
                      __bfloat162float(Xpb[grow * CC + (nh * 8 + j) * 16 + l15]);
            xv[rg][j] = v; s += v; q += v * v;
        }
#pragma unroll
        for (int o = 8; o > 0; o >>= 1) { s += __shfl_xor(s, o); q += __shfl_xor(q, o); }
        if (l15 == 0) {
            int rl = ri * 16 + lh * 4 + rg;
            red[nh][rl][0] = s; red[nh][rl][1] = q;
        }
    }
    __syncthreads();
    if (t < 32) {
        float S = red[0][t][0] + red[1][t][0];
        float Q = red[0][t][1] + red[1][t][1];
        float mu = S * (1.f / CC);
        float var = Q * (1.f / CC) - mu * mu;
        mrs[t][0] = mu; mrs[t][1] = rsqrtf(var + EPSF);
    }
    __syncthreads();
#pragma unroll
    for (int rg = 0; rg < 4; ++rg) {
        int rl = ri * 16 + lh * 4 + rg;
        long grow = row0 + rl;
        float mu = mrs[rl][0], rs = mrs[rl][1];
#pragma unroll
        for (int j = 0; j < 8; ++j)
            Xnb[grow * CC + (nh * 8 + j) * 16 + l15] =
                __float2bfloat16((xv[rg][j] - mu) * rs * g1v[j] + be1v[j]);
    }
}

// ---------------------------------------------------------------------------
// m93/m151-class GEMM: C[M][NDIM] = A[M][KD] @ BT[NDIM][KD]^T, 128x128 tile,
// 4 waves (each 64x64), BK=32, reg-staged single-buffer LDS with XOR swizzle.
// EPI 0: C=bf16, relu(acc+bias). EPI 1: C=f32, acc+bias+Res. EPI 2: C += acc.
// Block remap: groups of (1<<GRL2) row-tiles x (1<<CTL2) col-tiles for L2.
template<int KD, int NDIM, int EPI, int GRL2, int CTL2>
__global__ __launch_bounds__(256) void k_gemm(
    const __hip_bfloat16* __restrict__ A,
    const __hip_bfloat16* __restrict__ BT,
    const float* __restrict__ bias,
    const __hip_bfloat16* __restrict__ Res,
    void* __restrict__ Cout) {
    __shared__ short As[4096];          // 8 KB  [128 rows][32 k] swizzled
    __shared__ short Bs[4096];          // 8 KB  [128 cols][32 k] swizzled

    const int t = threadIdx.x, w = t >> 6, l = t & 63;
    const int l15 = l & 15, lh = l >> 4;
    const int bid = blockIdx.x;
    const int wi = bid & ((1 << (GRL2 + CTL2)) - 1);
    const int rt = ((bid >> (GRL2 + CTL2)) << GRL2) | (wi & ((1 << GRL2) - 1));
    const int ct = wi >> GRL2;
    const int row0 = rt * 128, n0 = ct * 128;
    const int wr = w & 1, wc = w >> 1;

    // staging: 512 chunks of 16B per tile; thread t owns chunks {t, t+256}
    const int ar = t >> 2;                       // 0..63 (chunk row within half)
    const int ak = (t & 3) << 3;                 // k element offset
    const int dbase = (ar * 64 + ((t & 3) << 4)) ^ ((ar & 7) << 4);
    const __hip_bfloat16* Ap = A + (long)(row0 + ar) * KD + ak;
    const __hip_bfloat16* Bp = BT + (long)(n0 + ar) * KD + ak;

    bf16x8 ra0 = *(const bf16x8*)(Ap);
    bf16x8 ra1 = *(const bf16x8*)(Ap + (long)64 * KD);
    bf16x8 rb0 = *(const bf16x8*)(Bp);
    bf16x8 rb1 = *(const bf16x8*)(Bp + (long)64 * KD);

    int offA[4], offB[4];
#pragma unroll
    for (int f = 0; f < 4; ++f) {
        int rowA = wr * 64 + f * 16 + l15;
        offA[f] = (rowA * 64 + lh * 16) ^ ((rowA & 7) << 4);
        int rowB = wc * 64 + f * 16 + l15;
        offB[f] = (rowB * 64 + lh * 16) ^ ((rowB & 7) << 4);
    }

    f32x4 acc[4][4];
#pragma unroll
    for (int i = 0; i < 4; ++i)
#pragma unroll
        for (int j = 0; j < 4; ++j) acc[i][j] = (f32x4)(0.f);

    constexpr int KS = KD / 32;
#pragma unroll 1
    for (int ks = 0; ks < KS; ++ks) {
        __syncthreads();                          // prev iter's ds_reads done
        // write tile ks (regs loaded last iter; vmcnt covered by compute)
        *(bf16x8*)((char*)As + dbase)        = ra0;
        *(bf16x8*)((char*)As + 4096 + dbase) = ra1;
        *(bf16x8*)((char*)Bs + dbase)        = rb0;
        *(bf16x8*)((char*)Bs + 4096 + dbase) = rb1;
        // issue tile ks+1 global loads (land during this iter's MFMAs)
        if (ks + 1 < KS) {
            const __hip_bfloat16* Ap2 = Ap + (ks + 1) * 32;
            const __hip_bfloat16* Bp2 = Bp + (ks + 1) * 32;
            ra0 = *(const bf16x8*)(Ap2);
            ra1 = *(const bf16x8*)(Ap2 + (long)64 * KD);
            rb0 = *(const bf16x8*)(Bp2);
            rb1 = *(const bf16x8*)(Bp2 + (long)64 * KD);
        }
        __syncthreads();                          // tile ks visible
        bf16x8 af[4], bfr[4];
#pragma unroll
        for (int f = 0; f < 4; ++f)
            af[f] = *(const bf16x8*)((const char*)As + offA[f]);
#pragma unroll
        for (int f = 0; f < 4; ++f)
            bfr[f] = *(const bf16x8*)((const char*)Bs + offB[f]);
#pragma unroll
        for (int fr = 0; fr < 4; ++fr)
#pragma unroll
            for (int fc = 0; fc < 4; ++fc)
                acc[fr][fc] = __builtin_amdgcn_mfma_f32_16x16x32_bf16(
                    af[fr], bfr[fc], acc[fr][fc], 0, 0, 0);
    }

    // ---- epilogue ----
#pragma unroll
    for (int fc = 0; fc < 4; ++fc) {
        int col = n0 + wc * 64 + fc * 16 + l15;
        float bv = (EPI == 2) ? 0.f : bias[col];
#pragma unroll
        for (int fr = 0; fr < 4; ++fr)
#pragma unroll
            for (int rg = 0; rg < 4; ++rg) {
                int row = wr * 64 + fr * 16 + lh * 4 + rg;
                long gi = (long)(row0 + row) * NDIM + col;
                if (EPI == 0) {
                    ((__hip_bfloat16*)Cout)[gi] =
                        __float2bfloat16(fmaxf(acc[fr][fc][rg] + bv, 0.f));
                } else if (EPI == 1) {
                    ((float*)Cout)[gi] =
                        acc[fr][fc][rg] + bv + __bfloat162float(Res[gi]);
                } else {
                    ((float*)Cout)[gi] += acc[fr][fc][rg];
                }
            }
    }
}

// ---------------------------------------------------------------------------
// Row LayerNorm over [ROWS][256] fp32, in place. 4 waves/block, 4 rows/wave.
__global__ __launch_bounds__(256) void k_ln(float* __restrict__ io,
                                            const float* __restrict__ g2,
                                            const float* __restrict__ be2) {
    const int t = threadIdx.x, w = t >> 6, l = t & 63;
    const int row0 = blockIdx.x * 16 + w * 4;
    float4 gv = ((const float4*)g2)[l];
    float4 bv = ((const float4*)be2)[l];
#pragma unroll
    for (int rr = 0; rr < 4; ++rr) {
        long base = (long)(row0 + rr) * CC;
        float4 v = *(float4*)&io[base + l * 4];
        float s = v.x + v.y + v.z + v.w;
        float q = v.x * v.x + v.y * v.y + v.z * v.z + v.w * v.w;
#pragma unroll
        for (int o = 32; o > 0; o >>= 1) { s += __shfl_xor(s, o); q += __shfl_xor(q, o); }
        float mu = s * (1.f / CC);
        float var = q * (1.f / CC) - mu * mu;
        float rs = rsqrtf(var + EPSF);
        float4 o4;
        o4.x = (v.x - mu) * rs * gv.x + bv.x;
        o4.y = (v.y - mu) * rs * gv.y + bv.y;
        o4.z = (v.z - mu) * rs * gv.z + bv.z;
        o4.w = (v.w - mu) * rs * gv.w + bv.w;
        *(float4*)&io[base + l * 4] = o4;
    }
}

// ---------------------------------------------------------------------------
extern "C" void kernel_launch(void* const* d_in, const int* in_sizes, int n_in,
                              void* d_out, int out_size, void* d_ws, size_t ws_size,
                              hipStream_t stream) {
    const float* X   = (const float*)d_in[0];
    const int*   sel = (const int*)d_in[1];
    const float* pe  = (const float*)d_in[3];
    const float* Wq  = (const float*)d_in[4];
    const float* bq  = (const float*)d_in[5];
    const float* Wk  = (const float*)d_in[6];
    const float* bk  = (const float*)d_in[7];
    const float* Wv  = (const float*)d_in[8];
    const float* bv  = (const float*)d_in[9];
    const float* Wo  = (const float*)d_in[10];
    const float* bo  = (const float*)d_in[11];
    const float* W1  = (const float*)d_in[12];
    const float* b1  = (const float*)d_in[13];
    const float* W2  = (const float*)d_in[14];
    const float* b2  = (const float*)d_in[15];
    const float* g1  = (const float*)d_in[16];
    const float* be1 = (const float*)d_in[17];
    const float* g2  = (const float*)d_in[18];
    const float* be2 = (const float*)d_in[19];

    float* out = (float*)d_out;
    char*  ws  = (char*)d_ws;

    __hip_bfloat16* Xpb = (__hip_bfloat16*)(ws);                  // 16 MB (Xp -> Xn in place)
    __hip_bfloat16* Qb  = (__hip_bfloat16*)(ws + (16 << 20));     // 4 MB
    __hip_bfloat16* Kb  = (__hip_bfloat16*)(ws + (20 << 20));     // 4 MB
    __hip_bfloat16* Vb  = (__hip_bfloat16*)(ws + (24 << 20));     // 4 MB
    __hip_bfloat16* ctxb= (__hip_bfloat16*)(ws + (28 << 20));     // 4 MB
    __hip_bfloat16* H   = (__hip_bfloat16*)(ws + (16 << 20));     // 32 MB (reuses Q/K/V/ctx after attn+projln)
    __hip_bfloat16* WqP = (__hip_bfloat16*)(ws + (48 << 20));     // 32 KB
    __hip_bfloat16* WkP = WqP + 16384;
    __hip_bfloat16* WvP = WkP + 16384;
    __hip_bfloat16* WoP = WvP + 16384;                            // 32 KB
    __hip_bfloat16* W1T = WoP + 16384;                            // 512 KB [1024][256]
    __hip_bfloat16* W2T = W1T + 262144;                           // 512 KB [2][256][512]
    float* attn_out = out + (long)ROWS * CC;

    k_pack_all<<<256, 256, 0, stream>>>(Wq, Wk, Wv, Wo, WqP, WkP, WvP, WoP);
    k_wt<<<2048, 256, 0, stream>>>(W1, W2, W1T, W2T);

    k_qkv<<<ROWS / 32, 256, 0, stream>>>((const float4*)X, (const float4*)pe,
                                         WqP, WkP, WvP, bq, bk, bv,
                                         Xpb, Qb, Kb, Vb);

    k_attn<<<ROWS / 4, 256, 0, stream>>>(Qb, Kb, Vb, sel, ctxb, attn_out);

    k_projln<<<ROWS / 32, 256, 0, stream>>>(ctxb, WoP, bo, g1, be1, Xpb, Xpb);

    // FFN: hidden split into two 512-col halves; H = [32768][512] bf16.
    // GEMM1 grid: 256 rt x 4 ct = 1024; GEMM2 grid: 256 rt x 2 ct = 512.
    // half 0
    k_gemm<256, 512, 0, 3, 2><<<1024, 256, 0, stream>>>(
        Xpb, W1T, b1, nullptr, (void*)H);
    k_gemm<512, 256, 1, 2, 1><<<512, 256, 0, stream>>>(
        H, W2T, b2, Xpb, (void*)out);
    // half 1
    k_gemm<256, 512, 0, 3, 2><<<1024, 256, 0, stream>>>(
        Xpb, W1T + (long)512 * 256, b1 + 512, nullptr, (void*)H);
    k_gemm<512, 256, 2, 2, 1><<<512, 256, 0, stream>>>(
        H, W2T + (long)512 * 256, b2, nullptr, (void*)out);

    k_ln<<<ROWS / 16, 256, 0, stream>>>(out, g2, be2);
}

// Round 10
// 146.940 us; speedup vs baseline: 1.1473x; 1.1473x over previous
//
#include <hip/hip_runtime.h>
#include <hip/hip_bf16.h>

#define CC 256
#define DD 64
#define PP 18
#define ROWS 32768
#define EPSF 1e-5f

typedef __attribute__((ext_vector_type(8))) short bf16x8;
typedef __attribute__((ext_vector_type(4))) short s16x4;
typedef __attribute__((ext_vector_type(4))) float f32x4;

// ---------------------------------------------------------------------------
// Merged weight prep (one dispatch):
//  i <  65536 : Wq/Wk/Wv/Wo -> 16x16 MFMA B-fragment order (bf16)
//  i >= 65536 : W1 -> W1T [1024][256] n-major; W2 -> W2T [2][256][512]
__global__ __launch_bounds__(256) void k_prep(
    const float* __restrict__ Wq, const float* __restrict__ Wk,
    const float* __restrict__ Wv, const float* __restrict__ Wo,
    const float* __restrict__ W1, const float* __restrict__ W2,
    __hip_bfloat16* __restrict__ WqP, __hip_bfloat16* __restrict__ WkP,
    __hip_bfloat16* __restrict__ WvP, __hip_bfloat16* __restrict__ WoP,
    __hip_bfloat16* __restrict__ W1T, __hip_bfloat16* __restrict__ W2T) {
    int i = blockIdx.x * 256 + threadIdx.x;
    if (i < 65536) {
        const float* src; __hip_bfloat16* dst; int K, N, j;
        if (i < 16384)      { src = Wq; dst = WqP; K = 256; N = 64;  j = i; }
        else if (i < 32768) { src = Wk; dst = WkP; K = 256; N = 64;  j = i - 16384; }
        else if (i < 49152) { src = Wv; dst = WvP; K = 256; N = 64;  j = i - 32768; }
        else                { src = Wo; dst = WoP; K = 64;  N = 256; j = i - 49152; }
        int e = j & 7, l = (j >> 3) & 63, rest = j >> 9;
        int KS = K >> 5;
        int ks = rest % KS, nt = rest / KS;
        int row = ks * 32 + (l >> 4) * 8 + e;
        int col = nt * 16 + (l & 15);
        dst[j] = __float2bfloat16(src[(long)row * N + col]);
    } else {
        int j = i - 65536;
        if (j < 262144) {
            int n = j >> 8, k = j & 255;
            W1T[j] = __float2bfloat16(W1[k * 1024 + n]);
        } else {
            int j2 = j - 262144;
            int h = j2 >> 17, n = (j2 >> 9) & 255, kk = j2 & 511;
            W2T[j2] = __float2bfloat16(W2[(long)(h * 512 + kk) * 256 + n]);
        }
    }
}

// ---------------------------------------------------------------------------
// Fused QKV. 32 rows/block, 4 waves, 16x16 MFMA, A-frags hoisted.
__global__ __launch_bounds__(256) void k_qkv(
    const float4* __restrict__ X4, const float4* __restrict__ pe4,
    const __hip_bfloat16* __restrict__ WqP, const __hip_bfloat16* __restrict__ WkP,
    const __hip_bfloat16* __restrict__ WvP,
    const float* __restrict__ bq, const float* __restrict__ bk,
    const float* __restrict__ bv,
    __hip_bfloat16* __restrict__ Xpb,
    __hip_bfloat16* __restrict__ Qb, __hip_bfloat16* __restrict__ Kb,
    __hip_bfloat16* __restrict__ Vb) {
    __shared__ short Xs[32 * 256];      // 16 KB, swizzled
    const int t = threadIdx.x, w = t >> 6, l = t & 63;
    const int l15 = l & 15, lh = l >> 4;
    const int row0 = blockIdx.x * 32;

    for (int j = t; j < 2048; j += 256) {          // 32 rows x 64 float4
        int r = j >> 6, c4 = j & 63;
        long g = row0 + r;
        float4 a = X4[(g << 6) + c4];
        float4 p = pe4[(long)((g & 16383) << 6) + c4];
        union { s16x4 v; __hip_bfloat16 h[4]; } u;
        u.h[0] = __float2bfloat16(a.x + p.x);
        u.h[1] = __float2bfloat16(a.y + p.y);
        u.h[2] = __float2bfloat16(a.z + p.z);
        u.h[3] = __float2bfloat16(a.w + p.w);
        int db = (r << 9) + (c4 << 3);
        db ^= (r & 7) << 4;
        *(s16x4*)((char*)Xs + db) = u.v;
        *(s16x4*)((char*)Xpb + (g << 9) + (c4 << 3)) = u.v;
    }
    __syncthreads();

    bf16x8 af[2][8];
#pragma unroll
    for (int ri = 0; ri < 2; ++ri)
#pragma unroll
        for (int ks = 0; ks < 8; ++ks) {
            int r = ri * 16 + l15;
            int db = (r << 9) + ks * 64 + lh * 16;
            db ^= (r & 7) << 4;
            af[ri][ks] = *(const bf16x8*)((const char*)Xs + db);
        }

    f32x4 acc[3][2];
#pragma unroll
    for (int j = 0; j < 3; ++j)
#pragma unroll
        for (int ri = 0; ri < 2; ++ri) acc[j][ri] = (f32x4)(0.f);

#pragma unroll
    for (int ks = 0; ks < 8; ++ks)
#pragma unroll
        for (int j = 0; j < 3; ++j) {
            int nt = w * 3 + j;
            const __hip_bfloat16* WP = (nt < 4) ? WqP : ((nt < 8) ? WkP : WvP);
            int ntl = nt & 3;
            bf16x8 b = *(const bf16x8*)(WP + (long)(((ntl * 8 + ks) << 6) + l) * 8);
#pragma unroll
            for (int ri = 0; ri < 2; ++ri)
                acc[j][ri] = __builtin_amdgcn_mfma_f32_16x16x32_bf16(
                    af[ri][ks], b, acc[j][ri], 0, 0, 0);
        }

#pragma unroll
    for (int j = 0; j < 3; ++j) {
        int nt = w * 3 + j;
        __hip_bfloat16* OP = (nt < 4) ? Qb : ((nt < 8) ? Kb : Vb);
        const float* BP = (nt < 4) ? bq : ((nt < 8) ? bk : bv);
        int col = (nt & 3) * 16 + l15;
        float bias = BP[col];
#pragma unroll
        for (int ri = 0; ri < 2; ++ri)
#pragma unroll
            for (int rg = 0; rg < 4; ++rg) {
                long row = row0 + ri * 16 + lh * 4 + rg;
                OP[row * DD + col] = __float2bfloat16(acc[j][ri][rg] + bias);
            }
    }
}

// ---------------------------------------------------------------------------
// Gather-attention v2, wave-parallel. One wave per token.
// Lane split: g = lane>>3 (row group), s = lane&7 (16B d-chunk).
// QK: 8 gathered rows per iter (3 iters cover 18), 3-step d reduce.
// Softmax: 3 exp per lane; group reduce 3 steps. PV: coalesced + broadcast.
__global__ __launch_bounds__(256) void k_attn(const __hip_bfloat16* __restrict__ Q,
                                              const __hip_bfloat16* __restrict__ K,
                                              const __hip_bfloat16* __restrict__ V,
                                              const int* __restrict__ sel,
                                              __hip_bfloat16* __restrict__ ctx,
                                              float* __restrict__ attn_out) {
    const int wave  = threadIdx.x >> 6;
    const int lane  = threadIdx.x & 63;
    const int token = blockIdx.x * 4 + wave;
    const int b     = token >> 14;
    const int g = lane >> 3, s = lane & 7;

    const int* selp = sel + (long)token * PP;
    int sel_l = (lane < PP) ? selp[lane] : 0;

    // q chunk -> 8 floats (d in [s*8, s*8+8))
    float qf[8];
    {
        uint4 qv = *(const uint4*)(Q + (long)token * DD + s * 8);
        qf[0] = __uint_as_float(qv.x << 16);
        qf[1] = __uint_as_float(qv.x & 0xffff0000u);
        qf[2] = __uint_as_float(qv.y << 16);
        qf[3] = __uint_as_float(qv.y & 0xffff0000u);
        qf[4] = __uint_as_float(qv.z << 16);
        qf[5] = __uint_as_float(qv.z & 0xffff0000u);
        qf[6] = __uint_as_float(qv.w << 16);
        qf[7] = __uint_as_float(qv.w & 0xffff0000u);
    }

    const __hip_bfloat16* Kbase = K + (((long)b << 14) * DD);
    float sc[3];
#pragma unroll
    for (int i = 0; i < 3; ++i) {
        int r = i * 8 + g;                         // 0..23; rows >=18 masked
        int idxr = __shfl(sel_l, r);
        uint4 kv = *(const uint4*)(Kbase + (long)idxr * DD + s * 8);
        float part;
        part = qf[0] * __uint_as_float(kv.x << 16);
        part = fmaf(qf[1], __uint_as_float(kv.x & 0xffff0000u), part);
        part = fmaf(qf[2], __uint_as_float(kv.y << 16), part);
        part = fmaf(qf[3], __uint_as_float(kv.y & 0xffff0000u), part);
        part = fmaf(qf[4], __uint_as_float(kv.z << 16), part);
        part = fmaf(qf[5], __uint_as_float(kv.z & 0xffff0000u), part);
        part = fmaf(qf[6], __uint_as_float(kv.w << 16), part);
        part = fmaf(qf[7], __uint_as_float(kv.w & 0xffff0000u), part);
        part += __shfl_xor(part, 1);
        part += __shfl_xor(part, 2);
        part += __shfl_xor(part, 4);
        sc[i] = (r < PP) ? part * 0.125f : -1e30f;
    }

    // softmax over 18 (values spread: row i*8+g lives in sc[i] of group g)
    float m = fmaxf(fmaxf(sc[0], sc[1]), sc[2]);
    m = fmaxf(m, __shfl_xor(m, 8));
    m = fmaxf(m, __shfl_xor(m, 16));
    m = fmaxf(m, __shfl_xor(m, 32));
    const float L2E = 1.4426950408889634f;
    float e0 = exp2f((sc[0] - m) * L2E);
    float e1 = exp2f((sc[1] - m) * L2E);
    float e2 = exp2f((sc[2] - m) * L2E);           // invalid rows -> exp2(-huge)=0
    float dsum = e0 + e1 + e2;
    dsum += __shfl_xor(dsum, 8);
    dsum += __shfl_xor(dsum, 16);
    dsum += __shfl_xor(dsum, 32);
    float inv = 1.f / dsum;

    // attention weights: attn[lane] for lane<18
    {
        int srcl = (lane & 7) << 3;                // group holding row lane
        float b0 = __shfl(e0, srcl);
        float b1 = __shfl(e1, srcl);
        float b2 = __shfl(e2, srcl);
        if (lane < PP) {
            float ev = (lane < 8) ? b0 : ((lane < 16) ? b1 : b2);
            attn_out[(long)token * PP + lane] = ev * inv;
        }
    }

    // ctx = (1/dsum) * sum_p e_p * V[idx_p]; lane owns dim d=lane.
    const __hip_bfloat16* Vbase = V + (((long)b << 14) * DD);
    float cvx = 0.f;
#pragma unroll
    for (int p = 0; p < PP; ++p) {
        float ep = (p < 8) ? e0 : ((p < 16) ? e1 : e2);     // static select
        float ap = __shfl(ep, (p & 7) << 3);
        int idxp = __shfl(sel_l, p);
        unsigned vv = *(const unsigned short*)(Vbase + (long)idxp * DD + lane);
        cvx = fmaf(ap, __uint_as_float(vv << 16), cvx);
    }
    ctx[(long)token * DD + lane] = __float2bfloat16(cvx * inv);
}

// ---------------------------------------------------------------------------
// proj + LN1: Xn = LN(Xpb + ctx@Wo + bo)*g1 + be1 -> bf16 (in-place on Xpb).
__global__ __launch_bounds__(256) void k_projln(
    const __hip_bfloat16* __restrict__ ctx, const __hip_bfloat16* __restrict__ WoP,
    const float* __restrict__ bo, const float* __restrict__ g1,
    const float* __restrict__ be1,
    const __hip_bfloat16* __restrict__ Xpb, __hip_bfloat16* __restrict__ Xnb) {
    __shared__ short Cs[32 * 64];       // 4 KB, swizzled
    __shared__ float red[2][32][2];
    __shared__ float mrs[32][2];
    const int t = threadIdx.x, w = t >> 6, l = t & 63;
    const int l15 = l & 15, lh = l >> 4;
    const int row0 = blockIdx.x * 32;

    {
        int r = t >> 3, ch = t & 7;                // 32 rows x 8 x 16B = 256
        int db = (r << 7) + (ch << 4);
        db ^= (r & 7) << 4;
        *(bf16x8*)((char*)Cs + db) = *(const bf16x8*)(ctx + (long)(row0 + r) * DD + ch * 8);
    }
    __syncthreads();

    const int ri = w & 1, nh = w >> 1;

    bf16x8 af[2];
#pragma unroll
    for (int ks = 0; ks < 2; ++ks) {
        int r = ri * 16 + l15;
        int db = (r << 7) + ks * 64 + lh * 16;
        db ^= (r & 7) << 4;
        af[ks] = *(const bf16x8*)((const char*)Cs + db);
    }

    f32x4 acc[8];
#pragma unroll
    for (int j = 0; j < 8; ++j) acc[j] = (f32x4)(0.f);

#pragma unroll
    for (int ks = 0; ks < 2; ++ks)
#pragma unroll
        for (int j = 0; j < 8; ++j) {
            int nt = nh * 8 + j;
            bf16x8 b = *(const bf16x8*)(WoP + (long)(((nt * 2 + ks) << 6) + l) * 8);
            acc[j] = __builtin_amdgcn_mfma_f32_16x16x32_bf16(af[ks], b, acc[j], 0, 0, 0);
        }

    float bov[8], g1v[8], be1v[8];
#pragma unroll
    for (int j = 0; j < 8; ++j) {
        int col = (nh * 8 + j) * 16 + l15;
        bov[j] = bo[col]; g1v[j] = g1[col]; be1v[j] = be1[col];
    }

    float xv[4][8];
#pragma unroll
    for (int rg = 0; rg < 4; ++rg) {
        long grow = row0 + ri * 16 + lh * 4 + rg;
        float s = 0.f, q = 0.f;
#pragma unroll
        for (int j = 0; j < 8; ++j) {
            float v = acc[j][rg] + bov[j] +
                      __bfloat162float(Xpb[grow * CC + (nh * 8 + j) * 16 + l15]);
            xv[rg][j] = v; s += v; q += v * v;
        }
#pragma unroll
        for (int o = 8; o > 0; o >>= 1) { s += __shfl_xor(s, o); q += __shfl_xor(q, o); }
        if (l15 == 0) {
            int rl = ri * 16 + lh * 4 + rg;
            red[nh][rl][0] = s; red[nh][rl][1] = q;
        }
    }
    __syncthreads();
    if (t < 32) {
        float S = red[0][t][0] + red[1][t][0];
        float Q = red[0][t][1] + red[1][t][1];
        float mu = S * (1.f / CC);
        float var = Q * (1.f / CC) - mu * mu;
        mrs[t][0] = mu; mrs[t][1] = rsqrtf(var + EPSF);
    }
    __syncthreads();
#pragma unroll
    for (int rg = 0; rg < 4; ++rg) {
        int rl = ri * 16 + lh * 4 + rg;
        long grow = row0 + rl;
        float mu = mrs[rl][0], rs = mrs[rl][1];
#pragma unroll
        for (int j = 0; j < 8; ++j)
            Xnb[grow * CC + (nh * 8 + j) * 16 + l15] =
                __float2bfloat16((xv[rg][j] - mu) * rs * g1v[j] + be1v[j]);
    }
}

// ---------------------------------------------------------------------------
// 128x128-tile GEMM: C[M][NDIM] = A[M][KD] @ BT[NDIM][KD]^T. 4 waves, BK=32,
// reg-staged single-buffer swizzled LDS. EPI: 0 relu+bias->bf16, 1 +bias+Res
// ->f32, 2 +=acc. Block remap for L2 grouping.
template<int KD, int NDIM, int EPI, int GRL2, int CTL2>
__global__ __launch_bounds__(256) void k_gemm(
    const __hip_bfloat16* __restrict__ A,
    const __hip_bfloat16* __restrict__ BT,
    const float* __restrict__ bias,
    const __hip_bfloat16* __restrict__ Res,
    void* __restrict__ Cout) {
    __shared__ short As[4096];          // 8 KB
    __shared__ short Bs[4096];          // 8 KB

    const int t = threadIdx.x, w = t >> 6, l = t & 63;
    const int l15 = l & 15, lh = l >> 4;
    const int bid = blockIdx.x;
    const int wi = bid & ((1 << (GRL2 + CTL2)) - 1);
    const int rt = ((bid >> (GRL2 + CTL2)) << GRL2) | (wi & ((1 << GRL2) - 1));
    const int ct = wi >> GRL2;
    const int row0 = rt * 128, n0 = ct * 128;
    const int wr = w & 1, wc = w >> 1;

    const int ar = t >> 2;
    const int ak = (t & 3) << 3;
    const int dbase = (ar * 64 + ((t & 3) << 4)) ^ ((ar & 7) << 4);
    const __hip_bfloat16* Ap = A + (long)(row0 + ar) * KD + ak;
    const __hip_bfloat16* Bp = BT + (long)(n0 + ar) * KD + ak;

    bf16x8 ra0 = *(const bf16x8*)(Ap);
    bf16x8 ra1 = *(const bf16x8*)(Ap + (long)64 * KD);
    bf16x8 rb0 = *(const bf16x8*)(Bp);
    bf16x8 rb1 = *(const bf16x8*)(Bp + (long)64 * KD);

    int offA[4], offB[4];
#pragma unroll
    for (int f = 0; f < 4; ++f) {
        int rowA = wr * 64 + f * 16 + l15;
        offA[f] = (rowA * 64 + lh * 16) ^ ((rowA & 7) << 4);
        int rowB = wc * 64 + f * 16 + l15;
        offB[f] = (rowB * 64 + lh * 16) ^ ((rowB & 7) << 4);
    }

    f32x4 acc[4][4];
#pragma unroll
    for (int i = 0; i < 4; ++i)
#pragma unroll
        for (int j = 0; j < 4; ++j) acc[i][j] = (f32x4)(0.f);

    constexpr int KS = KD / 32;
#pragma unroll 1
    for (int ks = 0; ks < KS; ++ks) {
        __syncthreads();
        *(bf16x8*)((char*)As + dbase)        = ra0;
        *(bf16x8*)((char*)As + 4096 + dbase) = ra1;
        *(bf16x8*)((char*)Bs + dbase)        = rb0;
        *(bf16x8*)((char*)Bs + 4096 + dbase) = rb1;
        if (ks + 1 < KS) {
            const __hip_bfloat16* Ap2 = Ap + (ks + 1) * 32;
            const __hip_bfloat16* Bp2 = Bp + (ks + 1) * 32;
            ra0 = *(const bf16x8*)(Ap2);
            ra1 = *(const bf16x8*)(Ap2 + (long)64 * KD);
            rb0 = *(const bf16x8*)(Bp2);
            rb1 = *(const bf16x8*)(Bp2 + (long)64 * KD);
        }
        __syncthreads();
        bf16x8 af[4], bfr[4];
#pragma unroll
        for (int f = 0; f < 4; ++f)
            af[f] = *(const bf16x8*)((const char*)As + offA[f]);
#pragma unroll
        for (int f = 0; f < 4; ++f)
            bfr[f] = *(const bf16x8*)((const char*)Bs + offB[f]);
#pragma unroll
        for (int fr = 0; fr < 4; ++fr)
#pragma unroll
            for (int fc = 0; fc < 4; ++fc)
                acc[fr][fc] = __builtin_amdgcn_mfma_f32_16x16x32_bf16(
                    af[fr], bfr[fc], acc[fr][fc], 0, 0, 0);
    }

#pragma unroll
    for (int fc = 0; fc < 4; ++fc) {
        int col = n0 + wc * 64 + fc * 16 + l15;
        float bv = (EPI == 2) ? 0.f : bias[col];
#pragma unroll
        for (int fr = 0; fr < 4; ++fr)
#pragma unroll
            for (int rg = 0; rg < 4; ++rg) {
                int row = wr * 64 + fr * 16 + lh * 4 + rg;
                long gi = (long)(row0 + row) * NDIM + col;
                if (EPI == 0) {
                    ((__hip_bfloat16*)Cout)[gi] =
                        __float2bfloat16(fmaxf(acc[fr][fc][rg] + bv, 0.f));
                } else if (EPI == 1) {
                    ((float*)Cout)[gi] =
                        acc[fr][fc][rg] + bv + __bfloat162float(Res[gi]);
                } else {
                    ((float*)Cout)[gi] += acc[fr][fc][rg];
                }
            }
    }
}

// ---------------------------------------------------------------------------
// Row LayerNorm over [ROWS][256] fp32, in place.
__global__ __launch_bounds__(256) void k_ln(float* __restrict__ io,
                                            const float* __restrict__ g2,
                                            const float* __restrict__ be2) {
    const int t = threadIdx.x, w = t >> 6, l = t & 63;
    const int row0 = blockIdx.x * 16 + w * 4;
    float4 gv = ((const float4*)g2)[l];
    float4 bv = ((const float4*)be2)[l];
#pragma unroll
    for (int rr = 0; rr < 4; ++rr) {
        long base = (long)(row0 + rr) * CC;
        float4 v = *(float4*)&io[base + l * 4];
        float s = v.x + v.y + v.z + v.w;
        float q = v.x * v.x + v.y * v.y + v.z * v.z + v.w * v.w;
#pragma unroll
        for (int o = 32; o > 0; o >>= 1) { s += __shfl_xor(s, o); q += __shfl_xor(q, o); }
        float mu = s * (1.f / CC);
        float var = q * (1.f / CC) - mu * mu;
        float rs = rsqrtf(var + EPSF);
        float4 o4;
        o4.x = (v.x - mu) * rs * gv.x + bv.x;
        o4.y = (v.y - mu) * rs * gv.y + bv.y;
        o4.z = (v.z - mu) * rs * gv.z + bv.z;
        o4.w = (v.w - mu) * rs * gv.w + bv.w;
        *(float4*)&io[base + l * 4] = o4;
    }
}

// ---------------------------------------------------------------------------
extern "C" void kernel_launch(void* const* d_in, const int* in_sizes, int n_in,
                              void* d_out, int out_size, void* d_ws, size_t ws_size,
                              hipStream_t stream) {
    const float* X   = (const float*)d_in[0];
    const int*   sel = (const int*)d_in[1];
    const float* pe  = (const float*)d_in[3];
    const float* Wq  = (const float*)d_in[4];
    const float* bq  = (const float*)d_in[5];
    const float* Wk  = (const float*)d_in[6];
    const float* bk  = (const float*)d_in[7];
    const float* Wv  = (const float*)d_in[8];
    const float* bv  = (const float*)d_in[9];
    const float* Wo  = (const float*)d_in[10];
    const float* bo  = (const float*)d_in[11];
    const float* W1  = (const float*)d_in[12];
    const float* b1  = (const float*)d_in[13];
    const float* W2  = (const float*)d_in[14];
    const float* b2  = (const float*)d_in[15];
    const float* g1  = (const float*)d_in[16];
    const float* be1 = (const float*)d_in[17];
    const float* g2  = (const float*)d_in[18];
    const float* be2 = (const float*)d_in[19];

    float* out = (float*)d_out;
    char*  ws  = (char*)d_ws;

    __hip_bfloat16* Xpb = (__hip_bfloat16*)(ws);                  // 16 MB (Xp -> Xn in place)
    __hip_bfloat16* Qb  = (__hip_bfloat16*)(ws + (16 << 20));     // 4 MB
    __hip_bfloat16* Kb  = (__hip_bfloat16*)(ws + (20 << 20));     // 4 MB
    __hip_bfloat16* Vb  = (__hip_bfloat16*)(ws + (24 << 20));     // 4 MB
    __hip_bfloat16* ctxb= (__hip_bfloat16*)(ws + (28 << 20));     // 4 MB
    __hip_bfloat16* H   = (__hip_bfloat16*)(ws + (16 << 20));     // 32 MB (reuses Q/K/V/ctx)
    __hip_bfloat16* WqP = (__hip_bfloat16*)(ws + (48 << 20));     // 32 KB
    __hip_bfloat16* WkP = WqP + 16384;
    __hip_bfloat16* WvP = WkP + 16384;
    __hip_bfloat16* WoP = WvP + 16384;                            // 32 KB
    __hip_bfloat16* W1T = WoP + 16384;                            // 512 KB [1024][256]
    __hip_bfloat16* W2T = W1T + 262144;                           // 512 KB [2][256][512]
    float* attn_out = out + (long)ROWS * CC;

    k_prep<<<2304, 256, 0, stream>>>(Wq, Wk, Wv, Wo, W1, W2,
                                     WqP, WkP, WvP, WoP, W1T, W2T);

    k_qkv<<<ROWS / 32, 256, 0, stream>>>((const float4*)X, (const float4*)pe,
                                         WqP, WkP, WvP, bq, bk, bv,
                                         Xpb, Qb, Kb, Vb);

    k_attn<<<ROWS / 4, 256, 0, stream>>>(Qb, Kb, Vb, sel, ctxb, attn_out);

    k_projln<<<ROWS / 32, 256, 0, stream>>>(ctxb, WoP, bo, g1, be1, Xpb, Xpb);

    // FFN: hidden split into two 512-col halves through H.
    k_gemm<256, 512, 0, 3, 2><<<1024, 256, 0, stream>>>(
        Xpb, W1T, b1, nullptr, (void*)H);
    k_gemm<512, 256, 1, 2, 1><<<512, 256, 0, stream>>>(
        H, W2T, b2, Xpb, (void*)out);
    k_gemm<256, 512, 0, 3, 2><<<1024, 256, 0, stream>>>(
        Xpb, W1T + (long)512 * 256, b1 + 512, nullptr, (void*)H);
    k_gemm<512, 256, 2, 2, 1><<<512, 256, 0, stream>>>(
        H, W2T + (long)512 * 256, b2, nullptr, (void*)out);

    k_ln<<<ROWS / 16, 256, 0, stream>>>(out, g2, be2);
}

// Round 11
// 120.100 us; speedup vs baseline: 1.4037x; 1.2235x over previous
//
#include <hip/hip_runtime.h>
#include <hip/hip_bf16.h>

#define CC 256
#define DD 64
#define PP 18
#define ROWS 32768
#define EPSF 1e-5f

typedef __attribute__((ext_vector_type(8))) short bf16x8;
typedef __attribute__((ext_vector_type(4))) short s16x4;
typedef __attribute__((ext_vector_type(4))) float f32x4;

// ---------------------------------------------------------------------------
// Merged weight prep (one dispatch, 768 blocks):
//  blocks 0..255   : Wq/Wk/Wv/Wo -> 16x16 MFMA B-fragment order (bf16)
//  blocks 256..511 : W1 [256][1024] -> W1T [1024][256]  (tiled transpose)
//  blocks 512..767 : W2 [1024][256] -> W2T [256][1024]  (tiled transpose)
__global__ __launch_bounds__(256) void k_prep(
    const float* __restrict__ Wq, const float* __restrict__ Wk,
    const float* __restrict__ Wv, const float* __restrict__ Wo,
    const float* __restrict__ W1, const float* __restrict__ W2,
    __hip_bfloat16* __restrict__ WqP, __hip_bfloat16* __restrict__ WkP,
    __hip_bfloat16* __restrict__ WvP, __hip_bfloat16* __restrict__ WoP,
    __hip_bfloat16* __restrict__ W1T, __hip_bfloat16* __restrict__ W2T) {
    __shared__ float tile[32][33];
    const int b = blockIdx.x, t = threadIdx.x;
    if (b < 256) {
        int i = b * 256 + t;
        const float* src; __hip_bfloat16* dst; int K, N, j;
        if (i < 16384)      { src = Wq; dst = WqP; K = 256; N = 64;  j = i; }
        else if (i < 32768) { src = Wk; dst = WkP; K = 256; N = 64;  j = i - 16384; }
        else if (i < 49152) { src = Wv; dst = WvP; K = 256; N = 64;  j = i - 32768; }
        else                { src = Wo; dst = WoP; K = 64;  N = 256; j = i - 49152; }
        int e = j & 7, l = (j >> 3) & 63, rest = j >> 9;
        int KS = K >> 5;
        int ks = rest % KS, nt = rest / KS;
        int row = ks * 32 + (l >> 4) * 8 + e;
        int col = nt * 16 + (l & 15);
        dst[j] = __float2bfloat16(src[(long)row * N + col]);
        return;
    }
    // tiled transpose
    const float* src; __hip_bfloat16* dst; int Nsrc, r0, c0, mode;
    if (b < 512) {          // W1: K=256 x N=1024 -> [1024][256]
        int bb = b - 256;   // 8 x 32 tiles
        r0 = (bb >> 5) * 32; c0 = (bb & 31) * 32;
        src = W1; dst = W1T; Nsrc = 1024; mode = 0;
    } else {                // W2: K=1024 x N=256 -> [256][1024]
        int bb = b - 512;   // 32 x 8 tiles
        r0 = (bb >> 3) * 32; c0 = (bb & 7) * 32;
        src = W2; dst = W2T; Nsrc = 256; mode = 1;
    }
#pragma unroll
    for (int i = 0; i < 4; ++i) {
        int idx = t + i * 256;
        int r = idx >> 5, c = idx & 31;
        tile[r][c] = src[(long)(r0 + r) * Nsrc + c0 + c];
    }
    __syncthreads();
#pragma unroll
    for (int i = 0; i < 4; ++i) {
        int idx = t + i * 256;
        int c2 = idx >> 5, r2 = idx & 31;
        long doff = (mode == 0) ? ((long)(c0 + c2) * 256 + r0 + r2)
                                : ((long)(c0 + c2) * 1024 + r0 + r2);
        dst[doff] = __float2bfloat16(tile[r2][c2]);
    }
}

// ---------------------------------------------------------------------------
// Fused QKV. 32 rows/block, 4 waves, 16x16 MFMA, A-frags hoisted.
__global__ __launch_bounds__(256) void k_qkv(
    const float4* __restrict__ X4, const float4* __restrict__ pe4,
    const __hip_bfloat16* __restrict__ WqP, const __hip_bfloat16* __restrict__ WkP,
    const __hip_bfloat16* __restrict__ WvP,
    const float* __restrict__ bq, const float* __restrict__ bk,
    const float* __restrict__ bv,
    __hip_bfloat16* __restrict__ Xpb,
    __hip_bfloat16* __restrict__ Qb, __hip_bfloat16* __restrict__ Kb,
    __hip_bfloat16* __restrict__ Vb) {
    __shared__ short Xs[32 * 256];      // 16 KB, swizzled
    const int t = threadIdx.x, w = t >> 6, l = t & 63;
    const int l15 = l & 15, lh = l >> 4;
    const int row0 = blockIdx.x * 32;

    for (int j = t; j < 2048; j += 256) {          // 32 rows x 64 float4
        int r = j >> 6, c4 = j & 63;
        long g = row0 + r;
        float4 a = X4[(g << 6) + c4];
        float4 p = pe4[(long)((g & 16383) << 6) + c4];
        union { s16x4 v; __hip_bfloat16 h[4]; } u;
        u.h[0] = __float2bfloat16(a.x + p.x);
        u.h[1] = __float2bfloat16(a.y + p.y);
        u.h[2] = __float2bfloat16(a.z + p.z);
        u.h[3] = __float2bfloat16(a.w + p.w);
        int db = (r << 9) + (c4 << 3);
        db ^= (r & 7) << 4;
        *(s16x4*)((char*)Xs + db) = u.v;
        *(s16x4*)((char*)Xpb + (g << 9) + (c4 << 3)) = u.v;
    }
    __syncthreads();

    bf16x8 af[2][8];
#pragma unroll
    for (int ri = 0; ri < 2; ++ri)
#pragma unroll
        for (int ks = 0; ks < 8; ++ks) {
            int r = ri * 16 + l15;
            int db = (r << 9) + ks * 64 + lh * 16;
            db ^= (r & 7) << 4;
            af[ri][ks] = *(const bf16x8*)((const char*)Xs + db);
        }

    f32x4 acc[3][2];
#pragma unroll
    for (int j = 0; j < 3; ++j)
#pragma unroll
        for (int ri = 0; ri < 2; ++ri) acc[j][ri] = (f32x4)(0.f);

#pragma unroll
    for (int ks = 0; ks < 8; ++ks)
#pragma unroll
        for (int j = 0; j < 3; ++j) {
            int nt = w * 3 + j;
            const __hip_bfloat16* WP = (nt < 4) ? WqP : ((nt < 8) ? WkP : WvP);
            int ntl = nt & 3;
            bf16x8 b = *(const bf16x8*)(WP + (long)(((ntl * 8 + ks) << 6) + l) * 8);
#pragma unroll
            for (int ri = 0; ri < 2; ++ri)
                acc[j][ri] = __builtin_amdgcn_mfma_f32_16x16x32_bf16(
                    af[ri][ks], b, acc[j][ri], 0, 0, 0);
        }

#pragma unroll
    for (int j = 0; j < 3; ++j) {
        int nt = w * 3 + j;
        __hip_bfloat16* OP = (nt < 4) ? Qb : ((nt < 8) ? Kb : Vb);
        const float* BP = (nt < 4) ? bq : ((nt < 8) ? bk : bv);
        int col = (nt & 3) * 16 + l15;
        float bias = BP[col];
#pragma unroll
        for (int ri = 0; ri < 2; ++ri)
#pragma unroll
            for (int rg = 0; rg < 4; ++rg) {
                long row = row0 + ri * 16 + lh * 4 + rg;
                OP[row * DD + col] = __float2bfloat16(acc[j][ri][rg] + bias);
            }
    }
}

// ---------------------------------------------------------------------------
// Gather-attention v3, wave-parallel with grouped PV. One wave per token.
// Lane split: g = lane>>3 (row group), s = lane&7 (16B d-chunk).
__global__ __launch_bounds__(256) void k_attn(const __hip_bfloat16* __restrict__ Q,
                                              const __hip_bfloat16* __restrict__ K,
                                              const __hip_bfloat16* __restrict__ V,
                                              const int* __restrict__ sel,
                                              __hip_bfloat16* __restrict__ ctx,
                                              float* __restrict__ attn_out) {
    const int wave  = threadIdx.x >> 6;
    const int lane  = threadIdx.x & 63;
    const int token = blockIdx.x * 4 + wave;
    const int b     = token >> 14;
    const int g = lane >> 3, s = lane & 7;

    const int* selp = sel + (long)token * PP;
    int sel_l = (lane < PP) ? selp[lane] : 0;

    float qf[8];
    {
        uint4 qv = *(const uint4*)(Q + (long)token * DD + s * 8);
        qf[0] = __uint_as_float(qv.x << 16);
        qf[1] = __uint_as_float(qv.x & 0xffff0000u);
        qf[2] = __uint_as_float(qv.y << 16);
        qf[3] = __uint_as_float(qv.y & 0xffff0000u);
        qf[4] = __uint_as_float(qv.z << 16);
        qf[5] = __uint_as_float(qv.z & 0xffff0000u);
        qf[6] = __uint_as_float(qv.w << 16);
        qf[7] = __uint_as_float(qv.w & 0xffff0000u);
    }

    const __hip_bfloat16* Kbase = K + (((long)b << 14) * DD);
    float sc[3];
    int idxs[3];
#pragma unroll
    for (int i = 0; i < 3; ++i) {
        int r = i * 8 + g;                         // 0..23; rows >=18 masked
        idxs[i] = __shfl(sel_l, r);
        uint4 kv = *(const uint4*)(Kbase + (long)idxs[i] * DD + s * 8);
        float part;
        part = qf[0] * __uint_as_float(kv.x << 16);
        part = fmaf(qf[1], __uint_as_float(kv.x & 0xffff0000u), part);
        part = fmaf(qf[2], __uint_as_float(kv.y << 16), part);
        part = fmaf(qf[3], __uint_as_float(kv.y & 0xffff0000u), part);
        part = fmaf(qf[4], __uint_as_float(kv.z << 16), part);
        part = fmaf(qf[5], __uint_as_float(kv.z & 0xffff0000u), part);
        part = fmaf(qf[6], __uint_as_float(kv.w << 16), part);
        part = fmaf(qf[7], __uint_as_float(kv.w & 0xffff0000u), part);
        part += __shfl_xor(part, 1);
        part += __shfl_xor(part, 2);
        part += __shfl_xor(part, 4);
        sc[i] = (r < PP) ? part * 0.125f : -1e30f;
    }

    float m = fmaxf(fmaxf(sc[0], sc[1]), sc[2]);
    m = fmaxf(m, __shfl_xor(m, 8));
    m = fmaxf(m, __shfl_xor(m, 16));
    m = fmaxf(m, __shfl_xor(m, 32));
    const float L2E = 1.4426950408889634f;
    float e0 = exp2f((sc[0] - m) * L2E);
    float e1 = exp2f((sc[1] - m) * L2E);
    float e2 = exp2f((sc[2] - m) * L2E);           // invalid rows -> 0
    float dsum = e0 + e1 + e2;
    dsum += __shfl_xor(dsum, 8);
    dsum += __shfl_xor(dsum, 16);
    dsum += __shfl_xor(dsum, 32);
    float inv = 1.f / dsum;

    // attention weights
    {
        int srcl = (lane & 7) << 3;
        float b0 = __shfl(e0, srcl);
        float b1 = __shfl(e1, srcl);
        float b2 = __shfl(e2, srcl);
        if (lane < PP) {
            float ev = (lane < 8) ? b0 : ((lane < 16) ? b1 : b2);
            attn_out[(long)token * PP + lane] = ev * inv;
        }
    }

    // grouped PV: group g handles rows {g, 8+g, 16+g} with this lane's e's.
    const __hip_bfloat16* Vbase = V + (((long)b << 14) * DD);
    float ca[8];
#pragma unroll
    for (int j = 0; j < 8; ++j) ca[j] = 0.f;
    float ev3[3] = {e0, e1, e2};
#pragma unroll
    for (int i = 0; i < 3; ++i) {
        uint4 vv = *(const uint4*)(Vbase + (long)idxs[i] * DD + s * 8);
        float e = ev3[i];
        ca[0] = fmaf(e, __uint_as_float(vv.x << 16), ca[0]);
        ca[1] = fmaf(e, __uint_as_float(vv.x & 0xffff0000u), ca[1]);
        ca[2] = fmaf(e, __uint_as_float(vv.y << 16), ca[2]);
        ca[3] = fmaf(e, __uint_as_float(vv.y & 0xffff0000u), ca[3]);
        ca[4] = fmaf(e, __uint_as_float(vv.z << 16), ca[4]);
        ca[5] = fmaf(e, __uint_as_float(vv.z & 0xffff0000u), ca[5]);
        ca[6] = fmaf(e, __uint_as_float(vv.w << 16), ca[6]);
        ca[7] = fmaf(e, __uint_as_float(vv.w & 0xffff0000u), ca[7]);
    }
#pragma unroll
    for (int o = 8; o <= 32; o <<= 1)
#pragma unroll
        for (int j = 0; j < 8; ++j) ca[j] += __shfl_xor(ca[j], o);
    if (g == 0) {
        union { bf16x8 v; __hip_bfloat16 h[8]; } u;
#pragma unroll
        for (int j = 0; j < 8; ++j) u.h[j] = __float2bfloat16(ca[j] * inv);
        *(bf16x8*)(ctx + (long)token * DD + s * 8) = u.v;
    }
}

// ---------------------------------------------------------------------------
// proj + LN1: Xn = LN(Xpb + ctx@Wo + bo)*g1 + be1 -> bf16 (in-place on Xpb).
__global__ __launch_bounds__(256) void k_projln(
    const __hip_bfloat16* __restrict__ ctx, const __hip_bfloat16* __restrict__ WoP,
    const float* __restrict__ bo, const float* __restrict__ g1,
    const float* __restrict__ be1,
    const __hip_bfloat16* __restrict__ Xpb, __hip_bfloat16* __restrict__ Xnb) {
    __shared__ short Cs[32 * 64];       // 4 KB, swizzled
    __shared__ float red[2][32][2];
    __shared__ float mrs[32][2];
    const int t = threadIdx.x, w = t >> 6, l = t & 63;
    const int l15 = l & 15, lh = l >> 4;
    const int row0 = blockIdx.x * 32;

    {
        int r = t >> 3, ch = t & 7;
        int db = (r << 7) + (ch << 4);
        db ^= (r & 7) << 4;
        *(bf16x8*)((char*)Cs + db) = *(const bf16x8*)(ctx + (long)(row0 + r) * DD + ch * 8);
    }
    __syncthreads();

    const int ri = w & 1, nh = w >> 1;

    bf16x8 af[2];
#pragma unroll
    for (int ks = 0; ks < 2; ++ks) {
        int r = ri * 16 + l15;
        int db = (r << 7) + ks * 64 + lh * 16;
        db ^= (r & 7) << 4;
        af[ks] = *(const bf16x8*)((const char*)Cs + db);
    }

    f32x4 acc[8];
#pragma unroll
    for (int j = 0; j < 8; ++j) acc[j] = (f32x4)(0.f);

#pragma unroll
    for (int ks = 0; ks < 2; ++ks)
#pragma unroll
        for (int j = 0; j < 8; ++j) {
            int nt = nh * 8 + j;
            bf16x8 b = *(const bf16x8*)(WoP + (long)(((nt * 2 + ks) << 6) + l) * 8);
            acc[j] = __builtin_amdgcn_mfma_f32_16x16x32_bf16(af[ks], b, acc[j], 0, 0, 0);
        }

    float bov[8], g1v[8], be1v[8];
#pragma unroll
    for (int j = 0; j < 8; ++j) {
        int col = (nh * 8 + j) * 16 + l15;
        bov[j] = bo[col]; g1v[j] = g1[col]; be1v[j] = be1[col];
    }

    float xv[4][8];
#pragma unroll
    for (int rg = 0; rg < 4; ++rg) {
        long grow = row0 + ri * 16 + lh * 4 + rg;
        float s = 0.f, q = 0.f;
#pragma unroll
        for (int j = 0; j < 8; ++j) {
            float v = acc[j][rg] + bov[j] +
                      __bfloat162float(Xpb[grow * CC + (nh * 8 + j) * 16 + l15]);
            xv[rg][j] = v; s += v; q += v * v;
        }
#pragma unroll
        for (int o = 8; o > 0; o >>= 1) { s += __shfl_xor(s, o); q += __shfl_xor(q, o); }
        if (l15 == 0) {
            int rl = ri * 16 + lh * 4 + rg;
            red[nh][rl][0] = s; red[nh][rl][1] = q;
        }
    }
    __syncthreads();
    if (t < 32) {
        float S = red[0][t][0] + red[1][t][0];
        float Q = red[0][t][1] + red[1][t][1];
        float mu = S * (1.f / CC);
        float var = Q * (1.f / CC) - mu * mu;
        mrs[t][0] = mu; mrs[t][1] = rsqrtf(var + EPSF);
    }
    __syncthreads();
#pragma unroll
    for (int rg = 0; rg < 4; ++rg) {
        int rl = ri * 16 + lh * 4 + rg;
        long grow = row0 + rl;
        float mu = mrs[rl][0], rs = mrs[rl][1];
#pragma unroll
        for (int j = 0; j < 8; ++j)
            Xnb[grow * CC + (nh * 8 + j) * 16 + l15] =
                __float2bfloat16((xv[rg][j] - mu) * rs * g1v[j] + be1v[j]);
    }
}

// ---------------------------------------------------------------------------
// GEMM1: C[M][NDIM] = A[M][KD] @ BT[NDIM][KD]^T, 128x128 tile, 4 waves,
// BK=32, reg-staged single-buffer swizzled LDS. EPI0: relu(acc+bias)->bf16.
template<int KD, int NDIM, int GRL2, int CTL2>
__global__ __launch_bounds__(256) void k_gemm(
    const __hip_bfloat16* __restrict__ A,
    const __hip_bfloat16* __restrict__ BT,
    const float* __restrict__ bias,
    __hip_bfloat16* __restrict__ Cout) {
    __shared__ short As[4096];          // 8 KB
    __shared__ short Bs[4096];          // 8 KB

    const int t = threadIdx.x, w = t >> 6, l = t & 63;
    const int l15 = l & 15, lh = l >> 4;
    const int bid = blockIdx.x;
    const int wi = bid & ((1 << (GRL2 + CTL2)) - 1);
    const int rt = ((bid >> (GRL2 + CTL2)) << GRL2) | (wi & ((1 << GRL2) - 1));
    const int ct = wi >> GRL2;
    const int row0 = rt * 128, n0 = ct * 128;
    const int wr = w & 1, wc = w >> 1;

    const int ar = t >> 2;
    const int ak = (t & 3) << 3;
    const int dbase = (ar * 64 + ((t & 3) << 4)) ^ ((ar & 7) << 4);
    const __hip_bfloat16* Ap = A + (long)(row0 + ar) * KD + ak;
    const __hip_bfloat16* Bp = BT + (long)(n0 + ar) * KD + ak;

    bf16x8 ra0 = *(const bf16x8*)(Ap);
    bf16x8 ra1 = *(const bf16x8*)(Ap + (long)64 * KD);
    bf16x8 rb0 = *(const bf16x8*)(Bp);
    bf16x8 rb1 = *(const bf16x8*)(Bp + (long)64 * KD);

    int offA[4], offB[4];
#pragma unroll
    for (int f = 0; f < 4; ++f) {
        int rowA = wr * 64 + f * 16 + l15;
        offA[f] = (rowA * 64 + lh * 16) ^ ((rowA & 7) << 4);
        int rowB = wc * 64 + f * 16 + l15;
        offB[f] = (rowB * 64 + lh * 16) ^ ((rowB & 7) << 4);
    }

    f32x4 acc[4][4];
#pragma unroll
    for (int i = 0; i < 4; ++i)
#pragma unroll
        for (int j = 0; j < 4; ++j) acc[i][j] = (f32x4)(0.f);

    constexpr int KS = KD / 32;
#pragma unroll 1
    for (int ks = 0; ks < KS; ++ks) {
        __syncthreads();
        *(bf16x8*)((char*)As + dbase)        = ra0;
        *(bf16x8*)((char*)As + 4096 + dbase) = ra1;
        *(bf16x8*)((char*)Bs + dbase)        = rb0;
        *(bf16x8*)((char*)Bs + 4096 + dbase) = rb1;
        if (ks + 1 < KS) {
            const __hip_bfloat16* Ap2 = Ap + (ks + 1) * 32;
            const __hip_bfloat16* Bp2 = Bp + (ks + 1) * 32;
            ra0 = *(const bf16x8*)(Ap2);
            ra1 = *(const bf16x8*)(Ap2 + (long)64 * KD);
            rb0 = *(const bf16x8*)(Bp2);
            rb1 = *(const bf16x8*)(Bp2 + (long)64 * KD);
        }
        __syncthreads();
        bf16x8 af[4], bfr[4];
#pragma unroll
        for (int f = 0; f < 4; ++f)
            af[f] = *(const bf16x8*)((const char*)As + offA[f]);
#pragma unroll
        for (int f = 0; f < 4; ++f)
            bfr[f] = *(const bf16x8*)((const char*)Bs + offB[f]);
#pragma unroll
        for (int fr = 0; fr < 4; ++fr)
#pragma unroll
            for (int fc = 0; fc < 4; ++fc)
                acc[fr][fc] = __builtin_amdgcn_mfma_f32_16x16x32_bf16(
                    af[fr], bfr[fc], acc[fr][fc], 0, 0, 0);
    }

#pragma unroll
    for (int fc = 0; fc < 4; ++fc) {
        int col = n0 + wc * 64 + fc * 16 + l15;
        float bv = bias[col];
#pragma unroll
        for (int fr = 0; fr < 4; ++fr)
#pragma unroll
            for (int rg = 0; rg < 4; ++rg) {
                int row = wr * 64 + fr * 16 + lh * 4 + rg;
                long gi = (long)(row0 + row) * NDIM + col;
                Cout[gi] = __float2bfloat16(fmaxf(acc[fr][fc][rg] + bv, 0.f));
            }
    }
}

// ---------------------------------------------------------------------------
// GEMM2 + residual + LN2 fused. out = LN(H @ W2 + b2 + Xn) * g2 + be2.
// Tile 128 rows x 256 cols (full row width -> LN in epilogue), 512 threads,
// 8 waves (wr = w>>2 in 0..1, wc = w&3 in 0..3; each wave 64x64).
// K = 1024, BK = 32, reg-staged single-buffer swizzled LDS.
__global__ __launch_bounds__(512) void k_gemm2ln(
    const __hip_bfloat16* __restrict__ A,      // H [32768][1024]
    const __hip_bfloat16* __restrict__ BT,     // W2T [256][1024]
    const float* __restrict__ b2,
    const __hip_bfloat16* __restrict__ Res,    // Xn bf16 [32768][256]
    const float* __restrict__ g2, const float* __restrict__ be2,
    float* __restrict__ out) {
    __shared__ short As[4096];          // 8 KB: 128 rows x 32 k
    __shared__ short Bs[8192];          // 16 KB: 256 cols x 32 k
    __shared__ float red[4][128][2];    // 4 KB
    __shared__ float mrs[128][2];

    const int t = threadIdx.x, w = t >> 6, l = t & 63;
    const int l15 = l & 15, lh = l >> 4;
    const int wr = w >> 2, wc = w & 3;
    const int row0 = blockIdx.x * 128;

    // staging: A 512 chunks (1/thread), B 1024 chunks (2/thread)
    const int ar = t >> 2;
    const int ak = (t & 3) << 3;
    const int dbA  = (ar * 64 + ((t & 3) << 4)) ^ ((ar & 7) << 4);
    const int br1  = ar + 128;
    const int dbB0 = dbA;
    const int dbB1 = (br1 * 64 + ((t & 3) << 4)) ^ ((br1 & 7) << 4);
    const __hip_bfloat16* Ap  = A  + (long)(row0 + ar) * 1024 + ak;
    const __hip_bfloat16* Bp0 = BT + (long)ar  * 1024 + ak;
    const __hip_bfloat16* Bp1 = BT + (long)br1 * 1024 + ak;

    bf16x8 ra  = *(const bf16x8*)(Ap);
    bf16x8 rb0 = *(const bf16x8*)(Bp0);
    bf16x8 rb1 = *(const bf16x8*)(Bp1);

    int offA[4], offB[4];
#pragma unroll
    for (int f = 0; f < 4; ++f) {
        int rowA = wr * 64 + f * 16 + l15;
        offA[f] = (rowA * 64 + lh * 16) ^ ((rowA & 7) << 4);
        int rowB = wc * 64 + f * 16 + l15;
        offB[f] = (rowB * 64 + lh * 16) ^ ((rowB & 7) << 4);
    }

    f32x4 acc[4][4];
#pragma unroll
    for (int i = 0; i < 4; ++i)
#pragma unroll
        for (int j = 0; j < 4; ++j) acc[i][j] = (f32x4)(0.f);

#pragma unroll 1
    for (int ks = 0; ks < 32; ++ks) {
        __syncthreads();
        *(bf16x8*)((char*)As + dbA)  = ra;
        *(bf16x8*)((char*)Bs + dbB0) = rb0;
        *(bf16x8*)((char*)Bs + dbB1) = rb1;
        if (ks + 1 < 32) {
            ra  = *(const bf16x8*)(Ap  + (ks + 1) * 32);
            rb0 = *(const bf16x8*)(Bp0 + (ks + 1) * 32);
            rb1 = *(const bf16x8*)(Bp1 + (ks + 1) * 32);
        }
        __syncthreads();
        bf16x8 af[4], bfr[4];
#pragma unroll
        for (int f = 0; f < 4; ++f)
            af[f] = *(const bf16x8*)((const char*)As + offA[f]);
#pragma unroll
        for (int f = 0; f < 4; ++f)
            bfr[f] = *(const bf16x8*)((const char*)Bs + offB[f]);
#pragma unroll
        for (int fr = 0; fr < 4; ++fr)
#pragma unroll
            for (int fc = 0; fc < 4; ++fc)
                acc[fr][fc] = __builtin_amdgcn_mfma_f32_16x16x32_bf16(
                    af[fr], bfr[fc], acc[fr][fc], 0, 0, 0);
    }

    // ---- epilogue: v = acc + b2 + Res; row LN across 256 cols ----
    float b2v[4], g2v[4], be2v[4];
#pragma unroll
    for (int fc = 0; fc < 4; ++fc) {
        int col = wc * 64 + fc * 16 + l15;
        b2v[fc] = b2[col]; g2v[fc] = g2[col]; be2v[fc] = be2[col];
    }
#pragma unroll
    for (int fr = 0; fr < 4; ++fr)
#pragma unroll
        for (int rg = 0; rg < 4; ++rg) {
            int row = wr * 64 + fr * 16 + lh * 4 + rg;
            float s = 0.f, q = 0.f;
#pragma unroll
            for (int fc = 0; fc < 4; ++fc) {
                long gi = (long)(row0 + row) * CC + wc * 64 + fc * 16 + l15;
                float v = acc[fr][fc][rg] + b2v[fc] + __bfloat162float(Res[gi]);
                acc[fr][fc][rg] = v;
                s += v; q += v * v;
            }
#pragma unroll
            for (int o = 8; o > 0; o >>= 1) {
                s += __shfl_xor(s, o); q += __shfl_xor(q, o);
            }
            if (l15 == 0) { red[wc][row][0] = s; red[wc][row][1] = q; }
        }
    __syncthreads();
    if (t < 128) {
        float S = 0.f, Q = 0.f;
#pragma unroll
        for (int ww = 0; ww < 4; ++ww) { S += red[ww][t][0]; Q += red[ww][t][1]; }
        float mu = S * (1.f / CC);
        float var = Q * (1.f / CC) - mu * mu;
        mrs[t][0] = mu; mrs[t][1] = rsqrtf(var + EPSF);
    }
    __syncthreads();
#pragma unroll
    for (int fr = 0; fr < 4; ++fr)
#pragma unroll
        for (int rg = 0; rg < 4; ++rg) {
            int row = wr * 64 + fr * 16 + lh * 4 + rg;
            float mu = mrs[row][0], rs = mrs[row][1];
#pragma unroll
            for (int fc = 0; fc < 4; ++fc) {
                long gi = (long)(row0 + row) * CC + wc * 64 + fc * 16 + l15;
                out[gi] = (acc[fr][fc][rg] - mu) * rs * g2v[fc] + be2v[fc];
            }
        }
}

// ---------------------------------------------------------------------------
extern "C" void kernel_launch(void* const* d_in, const int* in_sizes, int n_in,
                              void* d_out, int out_size, void* d_ws, size_t ws_size,
                              hipStream_t stream) {
    const float* X   = (const float*)d_in[0];
    const int*   sel = (const int*)d_in[1];
    const float* pe  = (const float*)d_in[3];
    const float* Wq  = (const float*)d_in[4];
    const float* bq  = (const float*)d_in[5];
    const float* Wk  = (const float*)d_in[6];
    const float* bk  = (const float*)d_in[7];
    const float* Wv  = (const float*)d_in[8];
    const float* bv  = (const float*)d_in[9];
    const float* Wo  = (const float*)d_in[10];
    const float* bo  = (const float*)d_in[11];
    const float* W1  = (const float*)d_in[12];
    const float* b1  = (const float*)d_in[13];
    const float* W2  = (const float*)d_in[14];
    const float* b2  = (const float*)d_in[15];
    const float* g1  = (const float*)d_in[16];
    const float* be1 = (const float*)d_in[17];
    const float* g2  = (const float*)d_in[18];
    const float* be2 = (const float*)d_in[19];

    float* out = (float*)d_out;
    char*  ws  = (char*)d_ws;       // ws_size ~= 256 MiB (observed via poison fill)

    __hip_bfloat16* Xpb = (__hip_bfloat16*)(ws);                  // 16 MB (Xp->Xn in place)
    __hip_bfloat16* Qb  = (__hip_bfloat16*)(ws + (16 << 20));     // 4 MB
    __hip_bfloat16* Kb  = (__hip_bfloat16*)(ws + (20 << 20));     // 4 MB
    __hip_bfloat16* Vb  = (__hip_bfloat16*)(ws + (24 << 20));     // 4 MB
    __hip_bfloat16* ctxb= (__hip_bfloat16*)(ws + (28 << 20));     // 4 MB
    __hip_bfloat16* H   = (__hip_bfloat16*)(ws + (16 << 20));     // 64 MB [32768][1024] (reuses QKV/ctx)
    __hip_bfloat16* WqP = (__hip_bfloat16*)(ws + (96 << 20));     // 32 KB
    __hip_bfloat16* WkP = WqP + 16384;
    __hip_bfloat16* WvP = WkP + 16384;
    __hip_bfloat16* WoP = WvP + 16384;                            // 32 KB
    __hip_bfloat16* W1T = WoP + 16384;                            // 512 KB [1024][256]
    __hip_bfloat16* W2T = W1T + 262144;                           // 512 KB [256][1024]
    float* attn_out = out + (long)ROWS * CC;

    k_prep<<<768, 256, 0, stream>>>(Wq, Wk, Wv, Wo, W1, W2,
                                    WqP, WkP, WvP, WoP, W1T, W2T);

    k_qkv<<<ROWS / 32, 256, 0, stream>>>((const float4*)X, (const float4*)pe,
                                         WqP, WkP, WvP, bq, bk, bv,
                                         Xpb, Qb, Kb, Vb);

    k_attn<<<ROWS / 4, 256, 0, stream>>>(Qb, Kb, Vb, sel, ctxb, attn_out);

    k_projln<<<ROWS / 32, 256, 0, stream>>>(ctxb, WoP, bo, g1, be1, Xpb, Xpb);

    // FFN: H = relu(Xn @ W1 + b1)  [one dispatch, N=1024]
    k_gemm<256, 1024, 3, 3><<<2048, 256, 0, stream>>>(Xpb, W1T, b1, H);
    // out = LN(H @ W2 + b2 + Xn) * g2 + be2  [one dispatch, fused LN]
    k_gemm2ln<<<256, 512, 0, stream>>>(H, W2T, b2, Xpb, g2, be2, out);
}

// Round 12
// 119.277 us; speedup vs baseline: 1.4134x; 1.0069x over previous
//
#include <hip/hip_runtime.h>
#include <hip/hip_bf16.h>

#define CC 256
#define DD 64
#define PP 18
#define ROWS 32768
#define EPSF 1e-5f

typedef __attribute__((ext_vector_type(8))) short bf16x8;
typedef __attribute__((ext_vector_type(4))) short s16x4;
typedef __attribute__((ext_vector_type(4))) float f32x4;

// Relaxed barrier: LDS handoff without draining vmcnt (keeps reg-staged
// global loads in flight across the barrier; compiler emits counted vmcnt
// at the next ds_write that consumes them).
#define BAR_LDS() do {                                        \
    asm volatile("s_waitcnt lgkmcnt(0)" ::: "memory");        \
    __builtin_amdgcn_s_barrier();                             \
    __builtin_amdgcn_sched_barrier(0);                        \
} while (0)

// ---------------------------------------------------------------------------
// Merged weight prep (one dispatch, 768 blocks):
//  blocks 0..255   : Wq/Wk/Wv/Wo -> 16x16 MFMA B-fragment order (bf16)
//  blocks 256..511 : W1 [256][1024] -> W1T [1024][256]  (tiled transpose)
//  blocks 512..767 : W2 [1024][256] -> W2T [256][1024]  (tiled transpose)
__global__ __launch_bounds__(256) void k_prep(
    const float* __restrict__ Wq, const float* __restrict__ Wk,
    const float* __restrict__ Wv, const float* __restrict__ Wo,
    const float* __restrict__ W1, const float* __restrict__ W2,
    __hip_bfloat16* __restrict__ WqP, __hip_bfloat16* __restrict__ WkP,
    __hip_bfloat16* __restrict__ WvP, __hip_bfloat16* __restrict__ WoP,
    __hip_bfloat16* __restrict__ W1T, __hip_bfloat16* __restrict__ W2T) {
    __shared__ float tile[32][33];
    const int b = blockIdx.x, t = threadIdx.x;
    if (b < 256) {
        int i = b * 256 + t;
        const float* src; __hip_bfloat16* dst; int K, N, j;
        if (i < 16384)      { src = Wq; dst = WqP; K = 256; N = 64;  j = i; }
        else if (i < 32768) { src = Wk; dst = WkP; K = 256; N = 64;  j = i - 16384; }
        else if (i < 49152) { src = Wv; dst = WvP; K = 256; N = 64;  j = i - 32768; }
        else                { src = Wo; dst = WoP; K = 64;  N = 256; j = i - 49152; }
        int e = j & 7, l = (j >> 3) & 63, rest = j >> 9;
        int KS = K >> 5;
        int ks = rest % KS, nt = rest / KS;
        int row = ks * 32 + (l >> 4) * 8 + e;
        int col = nt * 16 + (l & 15);
        dst[j] = __float2bfloat16(src[(long)row * N + col]);
        return;
    }
    const float* src; __hip_bfloat16* dst; int Nsrc, r0, c0, mode;
    if (b < 512) {          // W1: 256 x 1024 -> [1024][256]
        int bb = b - 256;
        r0 = (bb >> 5) * 32; c0 = (bb & 31) * 32;
        src = W1; dst = W1T; Nsrc = 1024; mode = 0;
    } else {                // W2: 1024 x 256 -> [256][1024]
        int bb = b - 512;
        r0 = (bb >> 3) * 32; c0 = (bb & 7) * 32;
        src = W2; dst = W2T; Nsrc = 256; mode = 1;
    }
#pragma unroll
    for (int i = 0; i < 4; ++i) {
        int idx = t + i * 256;
        int r = idx >> 5, c = idx & 31;
        tile[r][c] = src[(long)(r0 + r) * Nsrc + c0 + c];
    }
    __syncthreads();
#pragma unroll
    for (int i = 0; i < 4; ++i) {
        int idx = t + i * 256;
        int c2 = idx >> 5, r2 = idx & 31;
        long doff = (mode == 0) ? ((long)(c0 + c2) * 256 + r0 + r2)
                                : ((long)(c0 + c2) * 1024 + r0 + r2);
        dst[doff] = __float2bfloat16(tile[r2][c2]);
    }
}

// ---------------------------------------------------------------------------
// Fused QKV. 32 rows/block, 4 waves, 16x16 MFMA, A-frags hoisted.
__global__ __launch_bounds__(256) void k_qkv(
    const float4* __restrict__ X4, const float4* __restrict__ pe4,
    const __hip_bfloat16* __restrict__ WqP, const __hip_bfloat16* __restrict__ WkP,
    const __hip_bfloat16* __restrict__ WvP,
    const float* __restrict__ bq, const float* __restrict__ bk,
    const float* __restrict__ bv,
    __hip_bfloat16* __restrict__ Xpb,
    __hip_bfloat16* __restrict__ Qb, __hip_bfloat16* __restrict__ Kb,
    __hip_bfloat16* __restrict__ Vb) {
    __shared__ short Xs[32 * 256];      // 16 KB, swizzled
    const int t = threadIdx.x, w = t >> 6, l = t & 63;
    const int l15 = l & 15, lh = l >> 4;
    const int row0 = blockIdx.x * 32;

    for (int j = t; j < 2048; j += 256) {
        int r = j >> 6, c4 = j & 63;
        long g = row0 + r;
        float4 a = X4[(g << 6) + c4];
        float4 p = pe4[(long)((g & 16383) << 6) + c4];
        union { s16x4 v; __hip_bfloat16 h[4]; } u;
        u.h[0] = __float2bfloat16(a.x + p.x);
        u.h[1] = __float2bfloat16(a.y + p.y);
        u.h[2] = __float2bfloat16(a.z + p.z);
        u.h[3] = __float2bfloat16(a.w + p.w);
        int db = (r << 9) + (c4 << 3);
        db ^= (r & 7) << 4;
        *(s16x4*)((char*)Xs + db) = u.v;
        *(s16x4*)((char*)Xpb + (g << 9) + (c4 << 3)) = u.v;
    }
    __syncthreads();

    bf16x8 af[2][8];
#pragma unroll
    for (int ri = 0; ri < 2; ++ri)
#pragma unroll
        for (int ks = 0; ks < 8; ++ks) {
            int r = ri * 16 + l15;
            int db = (r << 9) + ks * 64 + lh * 16;
            db ^= (r & 7) << 4;
            af[ri][ks] = *(const bf16x8*)((const char*)Xs + db);
        }

    f32x4 acc[3][2];
#pragma unroll
    for (int j = 0; j < 3; ++j)
#pragma unroll
        for (int ri = 0; ri < 2; ++ri) acc[j][ri] = (f32x4)(0.f);

#pragma unroll
    for (int ks = 0; ks < 8; ++ks)
#pragma unroll
        for (int j = 0; j < 3; ++j) {
            int nt = w * 3 + j;
            const __hip_bfloat16* WP = (nt < 4) ? WqP : ((nt < 8) ? WkP : WvP);
            int ntl = nt & 3;
            bf16x8 b = *(const bf16x8*)(WP + (long)(((ntl * 8 + ks) << 6) + l) * 8);
#pragma unroll
            for (int ri = 0; ri < 2; ++ri)
                acc[j][ri] = __builtin_amdgcn_mfma_f32_16x16x32_bf16(
                    af[ri][ks], b, acc[j][ri], 0, 0, 0);
        }

#pragma unroll
    for (int j = 0; j < 3; ++j) {
        int nt = w * 3 + j;
        __hip_bfloat16* OP = (nt < 4) ? Qb : ((nt < 8) ? Kb : Vb);
        const float* BP = (nt < 4) ? bq : ((nt < 8) ? bk : bv);
        int col = (nt & 3) * 16 + l15;
        float bias = BP[col];
#pragma unroll
        for (int ri = 0; ri < 2; ++ri)
#pragma unroll
            for (int rg = 0; rg < 4; ++rg) {
                long row = row0 + ri * 16 + lh * 4 + rg;
                OP[row * DD + col] = __float2bfloat16(acc[j][ri][rg] + bias);
            }
    }
}

// ---------------------------------------------------------------------------
// Gather-attention v3, wave-parallel with grouped PV. One wave per token.
__global__ __launch_bounds__(256) void k_attn(const __hip_bfloat16* __restrict__ Q,
                                              const __hip_bfloat16* __restrict__ K,
                                              const __hip_bfloat16* __restrict__ V,
                                              const int* __restrict__ sel,
                                              __hip_bfloat16* __restrict__ ctx,
                                              float* __restrict__ attn_out) {
    const int wave  = threadIdx.x >> 6;
    const int lane  = threadIdx.x & 63;
    const int token = blockIdx.x * 4 + wave;
    const int b     = token >> 14;
    const int g = lane >> 3, s = lane & 7;

    const int* selp = sel + (long)token * PP;
    int sel_l = (lane < PP) ? selp[lane] : 0;

    float qf[8];
    {
        uint4 qv = *(const uint4*)(Q + (long)token * DD + s * 8);
        qf[0] = __uint_as_float(qv.x << 16);
        qf[1] = __uint_as_float(qv.x & 0xffff0000u);
        qf[2] = __uint_as_float(qv.y << 16);
        qf[3] = __uint_as_float(qv.y & 0xffff0000u);
        qf[4] = __uint_as_float(qv.z << 16);
        qf[5] = __uint_as_float(qv.z & 0xffff0000u);
        qf[6] = __uint_as_float(qv.w << 16);
        qf[7] = __uint_as_float(qv.w & 0xffff0000u);
    }

    const __hip_bfloat16* Kbase = K + (((long)b << 14) * DD);
    float sc[3];
    int idxs[3];
#pragma unroll
    for (int i = 0; i < 3; ++i) {
        int r = i * 8 + g;
        idxs[i] = __shfl(sel_l, r);
        uint4 kv = *(const uint4*)(Kbase + (long)idxs[i] * DD + s * 8);
        float part;
        part = qf[0] * __uint_as_float(kv.x << 16);
        part = fmaf(qf[1], __uint_as_float(kv.x & 0xffff0000u), part);
        part = fmaf(qf[2], __uint_as_float(kv.y << 16), part);
        part = fmaf(qf[3], __uint_as_float(kv.y & 0xffff0000u), part);
        part = fmaf(qf[4], __uint_as_float(kv.z << 16), part);
        part = fmaf(qf[5], __uint_as_float(kv.z & 0xffff0000u), part);
        part = fmaf(qf[6], __uint_as_float(kv.w << 16), part);
        part = fmaf(qf[7], __uint_as_float(kv.w & 0xffff0000u), part);
        part += __shfl_xor(part, 1);
        part += __shfl_xor(part, 2);
        part += __shfl_xor(part, 4);
        sc[i] = (r < PP) ? part * 0.125f : -1e30f;
    }

    float m = fmaxf(fmaxf(sc[0], sc[1]), sc[2]);
    m = fmaxf(m, __shfl_xor(m, 8));
    m = fmaxf(m, __shfl_xor(m, 16));
    m = fmaxf(m, __shfl_xor(m, 32));
    const float L2E = 1.4426950408889634f;
    float e0 = exp2f((sc[0] - m) * L2E);
    float e1 = exp2f((sc[1] - m) * L2E);
    float e2 = exp2f((sc[2] - m) * L2E);
    float dsum = e0 + e1 + e2;
    dsum += __shfl_xor(dsum, 8);
    dsum += __shfl_xor(dsum, 16);
    dsum += __shfl_xor(dsum, 32);
    float inv = 1.f / dsum;

    {
        int srcl = (lane & 7) << 3;
        float b0 = __shfl(e0, srcl);
        float b1 = __shfl(e1, srcl);
        float b2 = __shfl(e2, srcl);
        if (lane < PP) {
            float ev = (lane < 8) ? b0 : ((lane < 16) ? b1 : b2);
            attn_out[(long)token * PP + lane] = ev * inv;
        }
    }

    const __hip_bfloat16* Vbase = V + (((long)b << 14) * DD);
    float ca[8];
#pragma unroll
    for (int j = 0; j < 8; ++j) ca[j] = 0.f;
    float ev3[3] = {e0, e1, e2};
#pragma unroll
    for (int i = 0; i < 3; ++i) {
        uint4 vv = *(const uint4*)(Vbase + (long)idxs[i] * DD + s * 8);
        float e = ev3[i];
        ca[0] = fmaf(e, __uint_as_float(vv.x << 16), ca[0]);
        ca[1] = fmaf(e, __uint_as_float(vv.x & 0xffff0000u), ca[1]);
        ca[2] = fmaf(e, __uint_as_float(vv.y << 16), ca[2]);
        ca[3] = fmaf(e, __uint_as_float(vv.y & 0xffff0000u), ca[3]);
        ca[4] = fmaf(e, __uint_as_float(vv.z << 16), ca[4]);
        ca[5] = fmaf(e, __uint_as_float(vv.z & 0xffff0000u), ca[5]);
        ca[6] = fmaf(e, __uint_as_float(vv.w << 16), ca[6]);
        ca[7] = fmaf(e, __uint_as_float(vv.w & 0xffff0000u), ca[7]);
    }
#pragma unroll
    for (int o = 8; o <= 32; o <<= 1)
#pragma unroll
        for (int j = 0; j < 8; ++j) ca[j] += __shfl_xor(ca[j], o);
    if (g == 0) {
        union { bf16x8 v; __hip_bfloat16 h[8]; } u;
#pragma unroll
        for (int j = 0; j < 8; ++j) u.h[j] = __float2bfloat16(ca[j] * inv);
        *(bf16x8*)(ctx + (long)token * DD + s * 8) = u.v;
    }
}

// ---------------------------------------------------------------------------
// proj + LN1: Xn = LN(Xpb + ctx@Wo + bo)*g1 + be1 -> bf16 (in-place on Xpb).
__global__ __launch_bounds__(256) void k_projln(
    const __hip_bfloat16* __restrict__ ctx, const __hip_bfloat16* __restrict__ WoP,
    const float* __restrict__ bo, const float* __restrict__ g1,
    const float* __restrict__ be1,
    const __hip_bfloat16* __restrict__ Xpb, __hip_bfloat16* __restrict__ Xnb) {
    __shared__ short Cs[32 * 64];       // 4 KB, swizzled
    __shared__ float red[2][32][2];
    __shared__ float mrs[32][2];
    const int t = threadIdx.x, w = t >> 6, l = t & 63;
    const int l15 = l & 15, lh = l >> 4;
    const int row0 = blockIdx.x * 32;

    {
        int r = t >> 3, ch = t & 7;
        int db = (r << 7) + (ch << 4);
        db ^= (r & 7) << 4;
        *(bf16x8*)((char*)Cs + db) = *(const bf16x8*)(ctx + (long)(row0 + r) * DD + ch * 8);
    }
    __syncthreads();

    const int ri = w & 1, nh = w >> 1;

    bf16x8 af[2];
#pragma unroll
    for (int ks = 0; ks < 2; ++ks) {
        int r = ri * 16 + l15;
        int db = (r << 7) + ks * 64 + lh * 16;
        db ^= (r & 7) << 4;
        af[ks] = *(const bf16x8*)((const char*)Cs + db);
    }

    f32x4 acc[8];
#pragma unroll
    for (int j = 0; j < 8; ++j) acc[j] = (f32x4)(0.f);

#pragma unroll
    for (int ks = 0; ks < 2; ++ks)
#pragma unroll
        for (int j = 0; j < 8; ++j) {
            int nt = nh * 8 + j;
            bf16x8 b = *(const bf16x8*)(WoP + (long)(((nt * 2 + ks) << 6) + l) * 8);
            acc[j] = __builtin_amdgcn_mfma_f32_16x16x32_bf16(af[ks], b, acc[j], 0, 0, 0);
        }

    float bov[8], g1v[8], be1v[8];
#pragma unroll
    for (int j = 0; j < 8; ++j) {
        int col = (nh * 8 + j) * 16 + l15;
        bov[j] = bo[col]; g1v[j] = g1[col]; be1v[j] = be1[col];
    }

    float xv[4][8];
#pragma unroll
    for (int rg = 0; rg < 4; ++rg) {
        long grow = row0 + ri * 16 + lh * 4 + rg;
        float s = 0.f, q = 0.f;
#pragma unroll
        for (int j = 0; j < 8; ++j) {
            float v = acc[j][rg] + bov[j] +
                      __bfloat162float(Xpb[grow * CC + (nh * 8 + j) * 16 + l15]);
            xv[rg][j] = v; s += v; q += v * v;
        }
#pragma unroll
        for (int o = 8; o > 0; o >>= 1) { s += __shfl_xor(s, o); q += __shfl_xor(q, o); }
        if (l15 == 0) {
            int rl = ri * 16 + lh * 4 + rg;
            red[nh][rl][0] = s; red[nh][rl][1] = q;
        }
    }
    __syncthreads();
    if (t < 32) {
        float S = red[0][t][0] + red[1][t][0];
        float Q = red[0][t][1] + red[1][t][1];
        float mu = S * (1.f / CC);
        float var = Q * (1.f / CC) - mu * mu;
        mrs[t][0] = mu; mrs[t][1] = rsqrtf(var + EPSF);
    }
    __syncthreads();
#pragma unroll
    for (int rg = 0; rg < 4; ++rg) {
        int rl = ri * 16 + lh * 4 + rg;
        long grow = row0 + rl;
        float mu = mrs[rl][0], rs = mrs[rl][1];
#pragma unroll
        for (int j = 0; j < 8; ++j)
            Xnb[grow * CC + (nh * 8 + j) * 16 + l15] =
                __float2bfloat16((xv[rg][j] - mu) * rs * g1v[j] + be1v[j]);
    }
}

// ---------------------------------------------------------------------------
// GEMM1: C[M][NDIM] = A[M][KD] @ BT[NDIM][KD]^T, 128x128 tile, 4 waves,
// BK=32, reg-staged single-buffer swizzled LDS. EPI0: relu(acc+bias)->bf16.
template<int KD, int NDIM, int GRL2, int CTL2>
__global__ __launch_bounds__(256) void k_gemm(
    const __hip_bfloat16* __restrict__ A,
    const __hip_bfloat16* __restrict__ BT,
    const float* __restrict__ bias,
    __hip_bfloat16* __restrict__ Cout) {
    __shared__ short As[4096];
    __shared__ short Bs[4096];

    const int t = threadIdx.x, w = t >> 6, l = t & 63;
    const int l15 = l & 15, lh = l >> 4;
    const int bid = blockIdx.x;
    const int wi = bid & ((1 << (GRL2 + CTL2)) - 1);
    const int rt = ((bid >> (GRL2 + CTL2)) << GRL2) | (wi & ((1 << GRL2) - 1));
    const int ct = wi >> GRL2;
    const int row0 = rt * 128, n0 = ct * 128;
    const int wr = w & 1, wc = w >> 1;

    const int ar = t >> 2;
    const int ak = (t & 3) << 3;
    const int dbase = (ar * 64 + ((t & 3) << 4)) ^ ((ar & 7) << 4);
    const __hip_bfloat16* Ap = A + (long)(row0 + ar) * KD + ak;
    const __hip_bfloat16* Bp = BT + (long)(n0 + ar) * KD + ak;

    bf16x8 ra0 = *(const bf16x8*)(Ap);
    bf16x8 ra1 = *(const bf16x8*)(Ap + (long)64 * KD);
    bf16x8 rb0 = *(const bf16x8*)(Bp);
    bf16x8 rb1 = *(const bf16x8*)(Bp + (long)64 * KD);

    int offA[4], offB[4];
#pragma unroll
    for (int f = 0; f < 4; ++f) {
        int rowA = wr * 64 + f * 16 + l15;
        offA[f] = (rowA * 64 + lh * 16) ^ ((rowA & 7) << 4);
        int rowB = wc * 64 + f * 16 + l15;
        offB[f] = (rowB * 64 + lh * 16) ^ ((rowB & 7) << 4);
    }

    f32x4 acc[4][4];
#pragma unroll
    for (int i = 0; i < 4; ++i)
#pragma unroll
        for (int j = 0; j < 4; ++j) acc[i][j] = (f32x4)(0.f);

    constexpr int KS = KD / 32;
#pragma unroll 1
    for (int ks = 0; ks < KS; ++ks) {
        __syncthreads();
        *(bf16x8*)((char*)As + dbase)        = ra0;
        *(bf16x8*)((char*)As + 4096 + dbase) = ra1;
        *(bf16x8*)((char*)Bs + dbase)        = rb0;
        *(bf16x8*)((char*)Bs + 4096 + dbase) = rb1;
        if (ks + 1 < KS) {
            const __hip_bfloat16* Ap2 = Ap + (ks + 1) * 32;
            const __hip_bfloat16* Bp2 = Bp + (ks + 1) * 32;
            ra0 = *(const bf16x8*)(Ap2);
            ra1 = *(const bf16x8*)(Ap2 + (long)64 * KD);
            rb0 = *(const bf16x8*)(Bp2);
            rb1 = *(const bf16x8*)(Bp2 + (long)64 * KD);
        }
        __syncthreads();
        bf16x8 af[4], bfr[4];
#pragma unroll
        for (int f = 0; f < 4; ++f)
            af[f] = *(const bf16x8*)((const char*)As + offA[f]);
#pragma unroll
        for (int f = 0; f < 4; ++f)
            bfr[f] = *(const bf16x8*)((const char*)Bs + offB[f]);
#pragma unroll
        for (int fr = 0; fr < 4; ++fr)
#pragma unroll
            for (int fc = 0; fc < 4; ++fc)
                acc[fr][fc] = __builtin_amdgcn_mfma_f32_16x16x32_bf16(
                    af[fr], bfr[fc], acc[fr][fc], 0, 0, 0);
    }

#pragma unroll
    for (int fc = 0; fc < 4; ++fc) {
        int col = n0 + wc * 64 + fc * 16 + l15;
        float bv = bias[col];
#pragma unroll
        for (int fr = 0; fr < 4; ++fr)
#pragma unroll
            for (int rg = 0; rg < 4; ++rg) {
                int row = wr * 64 + fr * 16 + lh * 4 + rg;
                long gi = (long)(row0 + row) * NDIM + col;
                Cout[gi] = __float2bfloat16(fmaxf(acc[fr][fc][rg] + bv, 0.f));
            }
    }
}

// ---------------------------------------------------------------------------
// GEMM2 + residual + LN2 fused, v2: 64 rows x 256 cols per block (grid 512 =
// 2 blocks/CU), 512 threads, 8 waves (wr = w>>2: row half, wc = w&3: col
// quarter; each wave 32x64). K = 1024, BK = 32, reg-staged single-buffer
// swizzled LDS with RELAXED barriers (global loads stay in flight).
__global__ __launch_bounds__(512) void k_gemm2ln(
    const __hip_bfloat16* __restrict__ A,      // H [32768][1024]
    const __hip_bfloat16* __restrict__ BT,     // W2T [256][1024]
    const float* __restrict__ b2,
    const __hip_bfloat16* __restrict__ Res,    // Xn bf16 [32768][256]
    const float* __restrict__ g2, const float* __restrict__ be2,
    float* __restrict__ out) {
    __shared__ short As[64 * 32];       // 4 KB
    __shared__ short Bs[256 * 32];      // 16 KB
    __shared__ float red[4][64][2];     // 2 KB
    __shared__ float mrs[64][2];

    const int t = threadIdx.x, w = t >> 6, l = t & 63;
    const int l15 = l & 15, lh = l >> 4;
    const int wr = w >> 2, wc = w & 3;
    const int row0 = blockIdx.x * 64;
    const bool doA = (t < 256);

    // staging: A 256 chunks (threads 0..255), B 1024 chunks (2/thread)
    const int cr = t >> 2;              // 0..127
    const int ak = (t & 3) << 3;
    const int dbA  = ((t >> 2) * 64 + ((t & 3) << 4)) ^ (((t >> 2) & 7) << 4);
    const int brB0 = t >> 2;            // B rows 0..127
    const int brB1 = brB0 + 128;        // B rows 128..255
    const int dbB0 = (brB0 * 64 + ((t & 3) << 4)) ^ ((brB0 & 7) << 4);
    const int dbB1 = (brB1 * 64 + ((t & 3) << 4)) ^ ((brB1 & 7) << 4);
    const __hip_bfloat16* Ap  = A  + (long)(row0 + (t >> 2)) * 1024 + ak;  // rows 0..63 for t<256
    const __hip_bfloat16* Bp0 = BT + (long)brB0 * 1024 + ak;
    const __hip_bfloat16* Bp1 = BT + (long)brB1 * 1024 + ak;

    bf16x8 ra;
    if (doA) ra = *(const bf16x8*)(Ap);
    bf16x8 rb0 = *(const bf16x8*)(Bp0);
    bf16x8 rb1 = *(const bf16x8*)(Bp1);

    int offA[2], offB[4];
#pragma unroll
    for (int f = 0; f < 2; ++f) {
        int rowA = wr * 32 + f * 16 + l15;
        offA[f] = (rowA * 64 + lh * 16) ^ ((rowA & 7) << 4);
    }
#pragma unroll
    for (int f = 0; f < 4; ++f) {
        int rowB = wc * 64 + f * 16 + l15;
        offB[f] = (rowB * 64 + lh * 16) ^ ((rowB & 7) << 4);
    }

    f32x4 acc[2][4];
#pragma unroll
    for (int i = 0; i < 2; ++i)
#pragma unroll
        for (int j = 0; j < 4; ++j) acc[i][j] = (f32x4)(0.f);

#pragma unroll 1
    for (int ks = 0; ks < 32; ++ks) {
        BAR_LDS();                       // prev ds_reads done; vmcnt NOT drained
        if (doA) *(bf16x8*)((char*)As + dbA) = ra;   // counted vmcnt waits here
        *(bf16x8*)((char*)Bs + dbB0) = rb0;
        *(bf16x8*)((char*)Bs + dbB1) = rb1;
        if (ks + 1 < 32) {               // issue next tile; in flight across BAR
            if (doA) ra = *(const bf16x8*)(Ap + (ks + 1) * 32);
            rb0 = *(const bf16x8*)(Bp0 + (ks + 1) * 32);
            rb1 = *(const bf16x8*)(Bp1 + (ks + 1) * 32);
        }
        BAR_LDS();                       // ds_writes visible
        bf16x8 af[2], bfr[4];
#pragma unroll
        for (int f = 0; f < 2; ++f)
            af[f] = *(const bf16x8*)((const char*)As + offA[f]);
#pragma unroll
        for (int f = 0; f < 4; ++f)
            bfr[f] = *(const bf16x8*)((const char*)Bs + offB[f]);
#pragma unroll
        for (int fr = 0; fr < 2; ++fr)
#pragma unroll
            for (int fc = 0; fc < 4; ++fc)
                acc[fr][fc] = __builtin_amdgcn_mfma_f32_16x16x32_bf16(
                    af[fr], bfr[fc], acc[fr][fc], 0, 0, 0);
    }

    // ---- epilogue: v = acc + b2 + Res; row LN across 256 cols ----
    float b2v[4], g2v[4], be2v[4];
#pragma unroll
    for (int fc = 0; fc < 4; ++fc) {
        int col = wc * 64 + fc * 16 + l15;
        b2v[fc] = b2[col]; g2v[fc] = g2[col]; be2v[fc] = be2[col];
    }
#pragma unroll
    for (int fr = 0; fr < 2; ++fr)
#pragma unroll
        for (int rg = 0; rg < 4; ++rg) {
            int row = wr * 32 + fr * 16 + lh * 4 + rg;
            float s = 0.f, q = 0.f;
#pragma unroll
            for (int fc = 0; fc < 4; ++fc) {
                long gi = (long)(row0 + row) * CC + wc * 64 + fc * 16 + l15;
                float v = acc[fr][fc][rg] + b2v[fc] + __bfloat162float(Res[gi]);
                acc[fr][fc][rg] = v;
                s += v; q += v * v;
            }
#pragma unroll
            for (int o = 8; o > 0; o >>= 1) {
                s += __shfl_xor(s, o); q += __shfl_xor(q, o);
            }
            if (l15 == 0) { red[wc][row][0] = s; red[wc][row][1] = q; }
        }
    __syncthreads();
    if (t < 64) {
        float S = 0.f, Q = 0.f;
#pragma unroll
        for (int ww = 0; ww < 4; ++ww) { S += red[ww][t][0]; Q += red[ww][t][1]; }
        float mu = S * (1.f / CC);
        float var = Q * (1.f / CC) - mu * mu;
        mrs[t][0] = mu; mrs[t][1] = rsqrtf(var + EPSF);
    }
    __syncthreads();
#pragma unroll
    for (int fr = 0; fr < 2; ++fr)
#pragma unroll
        for (int rg = 0; rg < 4; ++rg) {
            int row = wr * 32 + fr * 16 + lh * 4 + rg;
            float mu = mrs[row][0], rs = mrs[row][1];
#pragma unroll
            for (int fc = 0; fc < 4; ++fc) {
                long gi = (long)(row0 + row) * CC + wc * 64 + fc * 16 + l15;
                out[gi] = (acc[fr][fc][rg] - mu) * rs * g2v[fc] + be2v[fc];
            }
        }
}

// ---------------------------------------------------------------------------
extern "C" void kernel_launch(void* const* d_in, const int* in_sizes, int n_in,
                              void* d_out, int out_size, void* d_ws, size_t ws_size,
                              hipStream_t stream) {
    const float* X   = (const float*)d_in[0];
    const int*   sel = (const int*)d_in[1];
    const float* pe  = (const float*)d_in[3];
    const float* Wq  = (const float*)d_in[4];
    const float* bq  = (const float*)d_in[5];
    const float* Wk  = (const float*)d_in[6];
    const float* bk  = (const float*)d_in[7];
    const float* Wv  = (const float*)d_in[8];
    const float* bv  = (const float*)d_in[9];
    const float* Wo  = (const float*)d_in[10];
    const float* bo  = (const float*)d_in[11];
    const float* W1  = (const float*)d_in[12];
    const float* b1  = (const float*)d_in[13];
    const float* W2  = (const float*)d_in[14];
    const float* b2  = (const float*)d_in[15];
    const float* g1  = (const float*)d_in[16];
    const float* be1 = (const float*)d_in[17];
    const float* g2  = (const float*)d_in[18];
    const float* be2 = (const float*)d_in[19];

    float* out = (float*)d_out;
    char*  ws  = (char*)d_ws;       // ws_size ~= 256 MiB

    __hip_bfloat16* Xpb = (__hip_bfloat16*)(ws);                  // 16 MB (Xp->Xn in place)
    __hip_bfloat16* Qb  = (__hip_bfloat16*)(ws + (16 << 20));     // 4 MB
    __hip_bfloat16* Kb  = (__hip_bfloat16*)(ws + (20 << 20));     // 4 MB
    __hip_bfloat16* Vb  = (__hip_bfloat16*)(ws + (24 << 20));     // 4 MB
    __hip_bfloat16* ctxb= (__hip_bfloat16*)(ws + (28 << 20));     // 4 MB
    __hip_bfloat16* H   = (__hip_bfloat16*)(ws + (16 << 20));     // 64 MB (reuses QKV/ctx)
    __hip_bfloat16* WqP = (__hip_bfloat16*)(ws + (96 << 20));     // 32 KB
    __hip_bfloat16* WkP = WqP + 16384;
    __hip_bfloat16* WvP = WkP + 16384;
    __hip_bfloat16* WoP = WvP + 16384;                            // 32 KB
    __hip_bfloat16* W1T = WoP + 16384;                            // 512 KB [1024][256]
    __hip_bfloat16* W2T = W1T + 262144;                           // 512 KB [256][1024]
    float* attn_out = out + (long)ROWS * CC;

    k_prep<<<768, 256, 0, stream>>>(Wq, Wk, Wv, Wo, W1, W2,
                                    WqP, WkP, WvP, WoP, W1T, W2T);

    k_qkv<<<ROWS / 32, 256, 0, stream>>>((const float4*)X, (const float4*)pe,
                                         WqP, WkP, WvP, bq, bk, bv,
                                         Xpb, Qb, Kb, Vb);

    k_attn<<<ROWS / 4, 256, 0, stream>>>(Qb, Kb, Vb, sel, ctxb, attn_out);

    k_projln<<<ROWS / 32, 256, 0, stream>>>(ctxb, WoP, bo, g1, be1, Xpb, Xpb);

    // FFN: H = relu(Xn @ W1 + b1)  [N=1024, 2048 blocks]
    k_gemm<256, 1024, 3, 3><<<2048, 256, 0, stream>>>(Xpb, W1T, b1, H);
    // out = LN(H @ W2 + b2 + Xn) * g2 + be2  [64-row tiles, 512 blocks]
    k_gemm2ln<<<512, 512, 0, stream>>>(H, W2T, b2, Xpb, g2, be2, out);
}